// Round 1
// baseline (721.014 us; speedup 1.0000x reference)
//
#include <hip/hip_runtime.h>
#include <hip/hip_cooperative_groups.h>
#include <stdint.h>

namespace cg = cooperative_groups;

#define BATCH 16
#define H 512
#define W 512
#define HW (H * W)
#define NTOT (BATCH * HW)
#define NWORDS (NTOT / 64)      // 65536 packed words, 8 per row, 4096 per image

#define TPB 256
#define NBLKW ((NWORDS + TPB - 1) / TPB)

#define SROWS 16                // CCL strip = 16 rows
#define SWORDS 128              // words per CCL strip
#define SPIX 8192               // pixels per CCL strip
#define NSTRIPS (NWORDS / SWORDS)   // 512 strips (never straddle images)
#define NBOUND (BATCH * 248)        // 3968 strip-boundary words

// ---------------------------------------------------------------------------
// Union-find (global): atomicMin keeps parent <= child (monotone) -> acyclic;
// stale plain reads only cost retries. find_root_c path-compresses.
// ---------------------------------------------------------------------------
__device__ __forceinline__ int find_root_c(int* L, int x) {
    int r = x, p = L[r];
    while (p != r) { r = p; p = L[r]; }
    if (L[x] != r) atomicMin(&L[x], r);
    return r;
}

__device__ void merge_uf(int* L, int a, int b) {
    while (true) {
        a = find_root_c(L, a);
        b = find_root_c(L, b);
        if (a == b) return;
        int lo = a < b ? a : b;
        int hi = a < b ? b : a;
        int old = atomicMin(&L[hi], lo);
        if (old == hi) return;
        a = lo; b = old;
    }
}

__device__ __forceinline__ int find_root_lds(int* P, int x) {
    int r = x, p = P[r];
    while (p != r) { r = p; p = P[r]; }
    return r;
}

__device__ void merge_lds(int* P, int a, int b) {
    while (true) {
        a = find_root_lds(P, a);
        b = find_root_lds(P, b);
        if (a == b) return;
        int lo = a < b ? a : b;
        int hi = a < b ? b : a;
        int old = atomicMin(&P[hi], lo);
        if (old == hi) return;
        a = lo; b = old;
    }
}

// start index of the run containing bit i of word m (base = pixel idx of bit0)
__device__ __forceinline__ int start_of(uint64_t m, int i, int cv, int base) {
    uint64_t below = i ? ((~m) & ((1ull << i) - 1)) : 0ull;
    if (below == 0) return (cv >= 0) ? cv : base;
    int hz = 63 - __builtin_clzll(below);
    return base + hz + 1;
}

// remove-small transform of one word (fg comps; pure function of CCL data)
__device__ uint64_t keep_word(const uint64_t* __restrict__ bits,
                              const int* __restrict__ carry, const int* __restrict__ L,
                              const int* __restrict__ sizes, const int* __restrict__ ncomp,
                              int minsz, int gw) {
    uint64_t m = bits[gw];
    uint64_t res = m;
    if (m && ncomp[gw >> 12] > 1) {
        int cv = carry[gw];
        int base = gw << 6;
        while (m) {
            int s = __builtin_ctzll(m);
            uint64_t rest = m >> s;
            uint64_t nr = ~rest;
            int len = nr ? __builtin_ctzll(nr) : (64 - s);
            uint64_t piece = ((len >= 64) ? ~0ull : ((1ull << len) - 1)) << s;
            int start = (s == 0 && cv >= 0) ? cv : (base + s);
            if (sizes[L[start]] < minsz) res &= ~piece;
            m &= ~piece;
        }
    }
    return res;
}

// fill-holes transform of one word (bg comps; needs inv=1 CCL data)
__device__ uint64_t fill_word(const uint64_t* __restrict__ bits,
                              const int* __restrict__ carry, const int* __restrict__ L,
                              const int* __restrict__ sizes, int minsz, int gw) {
    uint64_t fg = bits[gw];
    uint64_t bg = ~fg;
    uint64_t res = fg;
    int cv = carry[gw];
    int base = gw << 6;
    while (bg) {
        int s = __builtin_ctzll(bg);
        uint64_t rest = bg >> s;
        uint64_t nr = ~rest;
        int len = nr ? __builtin_ctzll(nr) : (64 - s);
        uint64_t piece = ((len >= 64) ? ~0ull : ((1ull << len) - 1)) << s;
        int start = (s == 0 && cv >= 0) ? cv : (base + s);
        if (sizes[L[start]] < minsz) res |= piece;
        bg &= ~piece;
    }
    return res;
}

// one morph output word from an LDS window; gyTop = global row of local row 0
template <int R, bool ERODE>
__device__ uint64_t morph_word_lds(const uint64_t* buf, int lrow, int w, int gyTop) {
    const uint64_t BORDER = ERODE ? ~0ull : 0ull;
    uint64_t res = ERODE ? ~0ull : 0ull;
#pragma unroll
    for (int dy = -R; dy <= R; ++dy) {
        int lr = lrow + dy;
        int gy = gyTop + lr;
        if (gy < 0 || gy >= H) continue;       // image border rows = identity
        int v = R * R - dy * dy;
        int kx = 0;
        while ((kx + 1) * (kx + 1) <= v) ++kx;
        uint64_t cur = buf[lr * 8 + w];
        uint64_t prv = (w > 0) ? buf[lr * 8 + w - 1] : BORDER;
        uint64_t nxt = (w < 7) ? buf[lr * 8 + w + 1] : BORDER;
        uint64_t acc = cur;
#pragma unroll
        for (int dx = 1; dx <= kx; ++dx) {
            uint64_t right = (cur >> dx) | (nxt << (64 - dx));
            uint64_t left  = (cur << dx) | (prv >> (64 - dx));
            if (ERODE) acc &= right & left;
            else       acc |= right | left;
        }
        if (ERODE) res &= acc;
        else       res |= acc;
    }
    return res;
}

// ---------------------------------------------------------------------------
// Strip-local CCL body (guarded: valid for blockDim 128 OR 256; threads with
// t >= SWORDS must pass m = 0 and just participate in the barriers).
// All intra-strip unions in LDS, publish depth-1 trees. par's first write
// happens after the second internal __syncthreads, so it may alias LDS that
// is read before the call.
// ---------------------------------------------------------------------------
__device__ void strip_ccl_body(uint64_t m, uint64_t* sw, int* scarry, int* par,
                               int blk, int t,
                               int* __restrict__ carry, int* __restrict__ L,
                               int* __restrict__ sizes, int* __restrict__ ncomp) {
    if (t < SWORDS) sw[t] = m;
    __syncthreads();

    if (t < SROWS) {                    // per-row carries
        int cv = -1;
        for (int i = 0; i < 8; ++i) {
            int lw = t * 8 + i;
            scarry[lw] = cv;
            uint64_t w = sw[lw];
            if (w >> 63) {
                uint64_t z = ~w;
                if (z == 0) { if (cv < 0) cv = lw << 6; }
                else { int hz = 63 - __builtin_clzll(z); cv = (lw << 6) + hz + 1; }
            } else cv = -1;
        }
    }
    __syncthreads();

    int lbase = t << 6;
    int cv = -1;
    uint64_t starts = 0ull;
    if (t < SWORDS) {
        cv = scarry[t];
        carry[blk * SWORDS + t] = (cv >= 0) ? (blk * SPIX + cv) : -1;
        starts = m & ~((m << 1) | ((cv >= 0) ? 1ull : 0ull));
        uint64_t ss = starts;
        while (ss) {
            int s = __builtin_ctzll(ss);
            par[lbase + s] = lbase + s;
            ss &= ss - 1;
        }
    }
    __syncthreads();

    if (t >= 8 && t < SWORDS && m) {    // intra-strip vertical unions
        uint64_t up = sw[t - 8];
        uint64_t cand = m & up;
        if (cand) {
            uint64_t curprev = (t & 7) ? sw[t - 1] : 0ull;
            uint64_t upprev  = (t & 7) ? sw[t - 9] : 0ull;
            uint64_t curl = (m << 1) | (curprev >> 63);
            uint64_t upl  = (up << 1) | (upprev >> 63);
            cand &= ~(curl & upl);
            int cvu = scarry[t - 8];
            while (cand) {
                int i = __builtin_ctzll(cand);
                int sP = start_of(m, i, cv, lbase);
                int sQ = start_of(up, i, cvu, lbase - 512);
                merge_lds(par, sP, sQ);
                cand &= cand - 1;
            }
        }
    }
    __syncthreads();

    if (t < SWORDS) {                   // publish depth-1 trees
        int gpix = blk * SPIX;
        uint64_t ss = starts;
        while (ss) {
            int s = __builtin_ctzll(ss);
            int ls = lbase + s;
            int r = find_root_lds(par, ls);
            L[gpix + ls] = gpix + r;
            if (r == ls) sizes[gpix + ls] = 0;
            ss &= ss - 1;
        }
    }
    if (t == 0 && (blk & 31) == 0) ncomp[blk >> 5] = 0;   // 32 strips per image
}

// one cross-strip boundary word (y % 16 == 0, y != 0)
__device__ void merge_bound_item(const uint64_t* __restrict__ bits, uint64_t inv64,
                                 const int* __restrict__ carry, int* __restrict__ L,
                                 int gw, int w) {
    uint64_t cur = bits[gw] ^ inv64;
    uint64_t up  = bits[gw - 8] ^ inv64;
    uint64_t cand = cur & up;
    if (!cand) return;
    uint64_t curprev = w ? (bits[gw - 1] ^ inv64) : 0ull;
    uint64_t upprev  = w ? (bits[gw - 9] ^ inv64) : 0ull;
    uint64_t curl = (cur << 1) | (curprev >> 63);
    uint64_t upl  = (up << 1)  | (upprev >> 63);
    cand &= ~(curl & upl);
    if (!cand) return;
    int cvc = carry[gw], cvu = carry[gw - 8];
    int base = gw << 6;
    while (cand) {
        int i = __builtin_ctzll(cand);
        int sP = start_of(cur, i, cvc, base);
        int sQ = start_of(up, i, cvu, base - W);
        merge_uf(L, sP, sQ);
        cand &= cand - 1;
    }
}

// flatten+count for one strip's 128 words (mega-kernel variant; per-block hash)
__device__ void flatten_block(const uint64_t* __restrict__ bits, uint64_t inv64,
                              const int* __restrict__ carry, int* __restrict__ L,
                              int* __restrict__ sizes, int* __restrict__ ncomp,
                              int blk, int t, int* hk, int* hv) {
    if (t < 128) { hk[t] = -1; hv[t] = 0; }
    __syncthreads();
    if (t < SWORDS) {
        int gw = blk * SWORDS + t;
        uint64_t m = bits[gw] ^ inv64;
        if (m) {
            int cv = carry[gw];
            int base = gw << 6;
            while (m) {
                int s = __builtin_ctzll(m);
                uint64_t rest = m >> s;
                uint64_t nr = ~rest;
                int len = nr ? __builtin_ctzll(nr) : (64 - s);
                uint64_t piece = ((len >= 64) ? ~0ull : ((1ull << len) - 1)) << s;
                bool initial = !(s == 0 && cv >= 0);
                int start = initial ? (base + s) : cv;
                int r = find_root_c(L, start);
                if (initial && r == start) atomicAdd(&ncomp[gw >> 12], 1);
                int cnt = __popcll(piece);
                uint32_t h = ((uint32_t)r * 2654435761u) >> 25;
                bool done = false;
                for (int tt = 0; tt < 16; ++tt) {
                    int slot = (h + tt) & 127;
                    int k = hk[slot];
                    if (k == -1) k = atomicCAS(&hk[slot], -1, r);
                    if (k == -1 || k == r) { atomicAdd(&hv[slot], cnt); done = true; break; }
                }
                if (!done) atomicAdd(&sizes[r], cnt);
                m &= ~piece;
            }
        }
    }
    __syncthreads();
    if (t < 128 && hk[t] != -1) atomicAdd(&sizes[hk[t]], hv[t]);
}

// keep + dilate(disk1) + float4 cast for one 8-row segment (256 threads)
__device__ void keep_dilate_seg(const uint64_t* __restrict__ bits,
                                const int* __restrict__ carry, const int* __restrict__ L,
                                const int* __restrict__ sizes, const int* __restrict__ ncomp,
                                float* __restrict__ out,
                                int img, int y0, int t, uint64_t* kb, uint64_t* db) {
    if (t < 80) {
        int lr = t >> 3;
        int w = t & 7;
        int gy = y0 - 1 + lr;
        uint64_t v = 0;
        if (gy >= 0 && gy < H)
            v = keep_word(bits, carry, L, sizes, ncomp, 2000, img * 4096 + gy * 8 + w);
        kb[t] = v;
    }
    __syncthreads();
    if (t < 64) {
        int r = t >> 3, w = t & 7;
        uint64_t cur = kb[(r + 1) * 8 + w];
        uint64_t up  = kb[r * 8 + w];
        uint64_t dn  = kb[(r + 2) * 8 + w];
        uint64_t prv = w ? kb[(r + 1) * 8 + w - 1] : 0ull;
        uint64_t nxt = (w < 7) ? kb[(r + 1) * 8 + w + 1] : 0ull;
        db[t] = cur | up | dn | (cur << 1) | (prv >> 63) | (cur >> 1) | (nxt << 63);
    }
    __syncthreads();

    int q0 = t * 16;                    // 16 consecutive pixels per thread
    uint64_t wd = db[q0 >> 6];
    int sh = q0 & 63;
    float4* o = (float4*)(out + (size_t)img * HW + (size_t)y0 * W + q0);
#pragma unroll
    for (int k = 0; k < 4; ++k) {
        uint32_t nib = (uint32_t)(wd >> (sh + k * 4)) & 0xFu;
        float4 f;
        f.x = (nib & 1u) ? 1.0f : 0.0f;
        f.y = (nib & 2u) ? 1.0f : 0.0f;
        f.z = (nib & 4u) ? 1.0f : 0.0f;
        f.w = (nib & 8u) ? 1.0f : 0.0f;
        o[k] = f;
    }
}

// ---------------------------------------------------------------------------
// MEGA: the whole pipeline as ONE cooperative kernel.
// grid = 512 blocks (one per CCL strip) x 256 threads; 10 grid.sync()s replace
// 10 kernel boundaries. LDS 34.3 KB + launch_bounds(256,2) -> 2 blocks/CU
// co-resident (512 = 256 CUs x 2), satisfying cooperative-launch residency.
// ---------------------------------------------------------------------------
__global__ __launch_bounds__(256, 2) void k_mega(
        const float4* __restrict__ in4, float* __restrict__ out,
        int* LA, int* sizesA, int* LB, int* sizesB,
        uint64_t* bits1, uint64_t* bits2, uint64_t* bits3,
        int* carryA, int* carryB, int* ncompA, int* ncompB) {
    cg::grid_group grid = cg::this_grid();
    __shared__ uint64_t sw[SWORDS];
    __shared__ int scarry[SWORDS];
    __shared__ union US {
        int par[SPIX];                                     // 32 KB (CCL)
        struct { uint64_t A[320]; uint64_t B[320]; } mo;   // 5 KB (morph)
        struct { int hk[128]; int hv[128]; } ha;           // 1 KB (flatten hash)
        struct { uint64_t kb[80]; uint64_t db[64]; } kd;   // 1.1 KB (out stage)
    } U;
    int blk = blockIdx.x;
    int t = threadIdx.x;
    int tid = blk * 256 + t;

    // P0: threshold + pack (fully coalesced float4 + 16-lane shfl nibble tree)
#pragma unroll
    for (int it = 0; it < 8; ++it) {
        int q = it * (NSTRIPS * 256) + tid;                // covers NTOT/4 quads
        float4 v = in4[q];
        uint32_t nib = (v.x > 0.0f ? 1u : 0u) | (v.y > 0.0f ? 2u : 0u) |
                       (v.z > 0.0f ? 4u : 0u) | (v.w > 0.0f ? 8u : 0u);
        uint64_t val = (uint64_t)nib << (4 * (t & 15));
        val |= __shfl_xor(val, 1);
        val |= __shfl_xor(val, 2);
        val |= __shfl_xor(val, 4);
        val |= __shfl_xor(val, 8);
        if ((t & 15) == 0) bits1[q >> 4] = val;
    }
    grid.sync();

    // P1: CCL1 strip phase (fg of bits1) -> set A
    {
        uint64_t m = (t < SWORDS) ? bits1[blk * SWORDS + t] : 0ull;
        strip_ccl_body(m, sw, scarry, U.par, blk, t, carryA, LA, sizesA, ncompA);
    }
    grid.sync();

    // P2: cross-strip merges (bits1, fg) — spread 3968 items over all blocks
    if (t < 8) {
        int item = blk * 8 + t;
        if (item < NBOUND) {
            int img = item / 248;
            int r = item - img * 248;
            int gw = img * 4096 + ((r >> 3) + 1) * SROWS * 8 + (r & 7);
            merge_bound_item(bits1, 0ull, carryA, LA, gw, r & 7);
        }
    }
    grid.sync();

    // P3: flatten + count (bits1, fg) -> sizesA, ncompA
    flatten_block(bits1, 0ull, carryA, LA, sizesA, ncompA, blk, t, U.ha.hk, U.ha.hv);
    grid.sync();

    // P4: remove_small_objects(2000,guard) -> bits2, fused with CCL2 strip (bg)
    {
        uint64_t m = 0ull;
        if (t < SWORDS) {
            int gw = blk * SWORDS + t;
            uint64_t kw = keep_word(bits1, carryA, LA, sizesA, ncompA, 2000, gw);
            bits2[gw] = kw;
            m = ~kw;
        }
        strip_ccl_body(m, sw, scarry, U.par, blk, t, carryB, LB, sizesB, ncompB);
    }
    grid.sync();

    // P5: cross-strip merges (bits2, bg)
    if (t < 8) {
        int item = blk * 8 + t;
        if (item < NBOUND) {
            int img = item / 248;
            int r = item - img * 248;
            int gw = img * 4096 + ((r >> 3) + 1) * SROWS * 8 + (r & 7);
            merge_bound_item(bits2, ~0ull, carryB, LB, gw, r & 7);
        }
    }
    grid.sync();

    // P6: flatten + count (bits2, bg) -> sizesB
    flatten_block(bits2, ~0ull, carryB, LB, sizesB, ncompB, blk, t, U.ha.hk, U.ha.hv);
    grid.sync();

    // P7: fill_holes(<301) + erode(d2) + opening(d5) + CCL3 strip -> bits3, set A
    {
        int img = blk >> 5, si = blk & 31;
        int gyTop = si * 16 - 12;
        for (int lw = t; lw < 320; lw += 256) {              // load + fill-holes
            int gy = gyTop + (lw >> 3);
            int w = lw & 7;
            uint64_t v = 0;
            if (gy >= 0 && gy < H)
                v = fill_word(bits2, carryB, LB, sizesB, 301, img * 4096 + gy * 8 + w);
            U.mo.A[lw] = v;
        }
        __syncthreads();
        for (int lw = t; lw < 320; lw += 256) {              // erode disk(2)
            int lr = lw >> 3;
            if (lr >= 2 && lr <= 37) U.mo.B[lw] = morph_word_lds<2, true>(U.mo.A, lr, lw & 7, gyTop);
        }
        __syncthreads();
        for (int lw = t; lw < 320; lw += 256) {              // erode disk(5)
            int lr = lw >> 3;
            if (lr >= 7 && lr <= 32) U.mo.A[lw] = morph_word_lds<5, true>(U.mo.B, lr, lw & 7, gyTop);
        }
        __syncthreads();
        for (int lw = t; lw < 320; lw += 256) {              // dilate disk(5)
            int lr = lw >> 3;
            if (lr >= 12 && lr <= 27) U.mo.B[lw] = morph_word_lds<5, false>(U.mo.A, lr, lw & 7, gyTop);
        }
        __syncthreads();
        uint64_t m3 = 0ull;
        if (t < SWORDS) {
            m3 = U.mo.B[t + 96];        // local rows 12..27 = this strip
            bits3[blk * SWORDS + t] = m3;
        }
        // par aliases mo — safe: all mo.B reads (m3) happen before body's first
        // par write, which is behind two __syncthreads
        strip_ccl_body(m3, sw, scarry, U.par, blk, t, carryA, LA, sizesA, ncompA);
    }
    grid.sync();

    // P8: cross-strip merges (bits3, fg)
    if (t < 8) {
        int item = blk * 8 + t;
        if (item < NBOUND) {
            int img = item / 248;
            int r = item - img * 248;
            int gw = img * 4096 + ((r >> 3) + 1) * SROWS * 8 + (r & 7);
            merge_bound_item(bits3, 0ull, carryA, LA, gw, r & 7);
        }
    }
    grid.sync();

    // P9: flatten + count (bits3, fg) -> sizesA, ncompA
    flatten_block(bits3, 0ull, carryA, LA, sizesA, ncompA, blk, t, U.ha.hk, U.ha.hv);
    grid.sync();

    // P10: remove_small_objects(2000,guard) + dilate(d1) + float4 out
    // 1024 8-row segments -> 2 per block
    for (int k = 0; k < 2; ++k) {
        int seg = blk * 2 + k;
        int img = seg >> 6, s8 = seg & 63;
        keep_dilate_seg(bits3, carryA, LA, sizesA, ncompA, out,
                        img, s8 * 8, t, U.kd.kb, U.kd.db);
        __syncthreads();
    }
}

// ---------------------------------------------------------------------------
// Legacy kernels (fallback path — identical to the proven 11-dispatch version)
// ---------------------------------------------------------------------------
__global__ void k_thresh_pack4(const float4* __restrict__ in4,
                               uint64_t* __restrict__ bits) {
    int q = blockIdx.x * blockDim.x + threadIdx.x;    // quad index (4 px)
    if (q >= NTOT / 4) return;
    float4 v = in4[q];
    uint32_t nib = (v.x > 0.0f ? 1u : 0u) | (v.y > 0.0f ? 2u : 0u) |
                   (v.z > 0.0f ? 4u : 0u) | (v.w > 0.0f ? 8u : 0u);
    uint64_t val = (uint64_t)nib << (4 * (threadIdx.x & 15));
    val |= __shfl_xor(val, 1);
    val |= __shfl_xor(val, 2);
    val |= __shfl_xor(val, 4);
    val |= __shfl_xor(val, 8);
    if ((threadIdx.x & 15) == 0) bits[q >> 4] = val;
}

__global__ void k_strip_ccl(const uint64_t* __restrict__ bits, int inv,
                            int* __restrict__ carry, int* __restrict__ L,
                            int* __restrict__ sizes, int* __restrict__ ncomp) {
    __shared__ uint64_t sw[SWORDS];
    __shared__ int scarry[SWORDS];
    __shared__ int par[SPIX];
    int blk = blockIdx.x;
    int t = threadIdx.x;
    uint64_t inv64 = inv ? ~0ull : 0ull;
    uint64_t m = bits[blk * SWORDS + t] ^ inv64;
    strip_ccl_body(m, sw, scarry, par, blk, t, carry, L, sizes, ncomp);
}

__global__ void k_keep_strip(const uint64_t* __restrict__ bits,
                             const int* __restrict__ carryIn, const int* __restrict__ Lin,
                             const int* __restrict__ sizesIn, const int* __restrict__ ncompIn,
                             uint64_t* __restrict__ outBits,
                             int* __restrict__ carryOut, int* __restrict__ Lout,
                             int* __restrict__ sizesOut, int* __restrict__ ncompOut) {
    __shared__ uint64_t sw[SWORDS];
    __shared__ int scarry[SWORDS];
    __shared__ int par[SPIX];
    int blk = blockIdx.x;
    int t = threadIdx.x;
    int gw = blk * SWORDS + t;
    uint64_t kw = keep_word(bits, carryIn, Lin, sizesIn, ncompIn, 2000, gw);
    outBits[gw] = kw;
    strip_ccl_body(~kw, sw, scarry, par, blk, t, carryOut, Lout, sizesOut, ncompOut);
}

__global__ void k_merge_bound(const uint64_t* __restrict__ bits, int inv,
                              const int* __restrict__ carry, int* __restrict__ L) {
    int tid = threadIdx.x;
    if (tid >= 248) return;             // 31 boundary rows x 8 words
    int img = blockIdx.x;
    int y = ((tid >> 3) + 1) * SROWS;
    int w = tid & 7;
    int gw = img * 4096 + y * 8 + w;
    uint64_t inv64 = inv ? ~0ull : 0ull;
    merge_bound_item(bits, inv64, carry, L, gw, w);
}

__global__ void k_flatten_count(const uint64_t* __restrict__ bits, int inv,
                                const int* __restrict__ carry, int* __restrict__ L,
                                int* __restrict__ sizes, int* __restrict__ ncomp) {
    __shared__ int hk[128];
    __shared__ int hv[128];
    for (int i = threadIdx.x; i < 128; i += TPB) { hk[i] = -1; hv[i] = 0; }
    __syncthreads();

    int gw = blockIdx.x * blockDim.x + threadIdx.x;
    if (gw < NWORDS) {
        uint64_t inv64 = inv ? ~0ull : 0ull;
        uint64_t m = bits[gw] ^ inv64;
        if (m) {
            int cv = carry[gw];
            int base = gw << 6;
            while (m) {
                int s = __builtin_ctzll(m);
                uint64_t rest = m >> s;
                uint64_t nr = ~rest;
                int len = nr ? __builtin_ctzll(nr) : (64 - s);
                uint64_t piece = ((len >= 64) ? ~0ull : ((1ull << len) - 1)) << s;
                bool initial = !(s == 0 && cv >= 0);
                int start = initial ? (base + s) : cv;
                int r = find_root_c(L, start);
                if (initial && r == start) atomicAdd(&ncomp[gw >> 12], 1);
                int cnt = __popcll(piece);
                uint32_t h = ((uint32_t)r * 2654435761u) >> 25;
                bool done = false;
                for (int tt = 0; tt < 16; ++tt) {
                    int slot = (h + tt) & 127;
                    int k = hk[slot];
                    if (k == -1) k = atomicCAS(&hk[slot], -1, r);
                    if (k == -1 || k == r) { atomicAdd(&hv[slot], cnt); done = true; break; }
                }
                if (!done) atomicAdd(&sizes[r], cnt);
                m &= ~piece;
            }
        }
    }
    __syncthreads();
    for (int i = threadIdx.x; i < 128; i += TPB)
        if (hk[i] != -1) atomicAdd(&sizes[hk[i]], hv[i]);
}

__global__ void k_fill_morph_ccl(const uint64_t* __restrict__ bits,
                                 const int* __restrict__ carryB, const int* __restrict__ LB,
                                 const int* __restrict__ sizesB,
                                 uint64_t* __restrict__ bits3,
                                 int* __restrict__ carryA, int* __restrict__ LA,
                                 int* __restrict__ sizesA, int* __restrict__ ncompA) {
    __shared__ uint64_t sw[SWORDS];
    __shared__ int scarry[SWORDS];
    __shared__ union {
        int par[SPIX];                                     // 32 KB (CCL)
        struct { uint64_t A[320]; uint64_t B[320]; } mo;   // 5 KB (morph)
    } U;
    int s = blockIdx.x;                 // strip id (32 per image)
    int t = threadIdx.x;
    int img = s >> 5, si = s & 31;
    int gyTop = si * 16 - 12;

    for (int lw = t; lw < 320; lw += SWORDS) {   // load + fill-holes
        int gy = gyTop + (lw >> 3);
        int w = lw & 7;
        uint64_t v = 0;
        if (gy >= 0 && gy < H)
            v = fill_word(bits, carryB, LB, sizesB, 301, img * 4096 + gy * 8 + w);
        U.mo.A[lw] = v;
    }
    __syncthreads();
    for (int lw = t; lw < 320; lw += SWORDS) {   // erode disk(2): rows 2..37
        int lr = lw >> 3;
        if (lr >= 2 && lr <= 37) U.mo.B[lw] = morph_word_lds<2, true>(U.mo.A, lr, lw & 7, gyTop);
    }
    __syncthreads();
    for (int lw = t; lw < 320; lw += SWORDS) {   // erode disk(5): rows 7..32
        int lr = lw >> 3;
        if (lr >= 7 && lr <= 32) U.mo.A[lw] = morph_word_lds<5, true>(U.mo.B, lr, lw & 7, gyTop);
    }
    __syncthreads();
    for (int lw = t; lw < 320; lw += SWORDS) {   // dilate disk(5): rows 12..27
        int lr = lw >> 3;
        if (lr >= 12 && lr <= 27) U.mo.B[lw] = morph_word_lds<5, false>(U.mo.A, lr, lw & 7, gyTop);
    }
    __syncthreads();
    uint64_t m3 = U.mo.B[t + 96];       // local rows 12..27 = this strip
    bits3[s * SWORDS + t] = m3;
    strip_ccl_body(m3, sw, scarry, U.par, s, t, carryA, LA, sizesA, ncompA);
}

__global__ void k_keep_dilate_float(const uint64_t* __restrict__ bits,
                                    const int* __restrict__ carry, const int* __restrict__ L,
                                    const int* __restrict__ sizes, const int* __restrict__ ncomp,
                                    float* __restrict__ out) {
    __shared__ uint64_t kb[10 * 8];     // rows y0-1 .. y0+8
    __shared__ uint64_t db[8 * 8];      // dilated output rows
    int blk = blockIdx.x;
    int img = blk >> 6;                 // 64 blocks per image
    int s = blk & 63;
    keep_dilate_seg(bits, carry, L, sizes, ncomp, out, img, s * 8, threadIdx.x, kb, db);
}

// ---------------------------------------------------------------------------
// Host side — 1 cooperative dispatch (fallback: legacy 11 dispatches)
// ---------------------------------------------------------------------------
extern "C" void kernel_launch(void* const* d_in, const int* in_sizes, int n_in,
                              void* d_out, int out_size, void* d_ws, size_t ws_size,
                              hipStream_t stream) {
    const float* in = (const float*)d_in[0];
    float* out = (float*)d_out;

    uint8_t* ws = (uint8_t*)d_ws;
    int* LA      = (int*)ws;                                  // 16 MB
    int* sizesA  = (int*)(ws + (size_t)NTOT * 4);             // 16 MB
    int* LB      = (int*)(ws + (size_t)NTOT * 8);             // 16 MB
    int* sizesB  = (int*)(ws + (size_t)NTOT * 12);            // 16 MB
    uint64_t* bits1 = (uint64_t*)(ws + (size_t)NTOT * 16);    // 512 KB
    uint64_t* bits2 = bits1 + NWORDS;                         // 512 KB
    uint64_t* bits3 = bits2 + NWORDS;                         // 512 KB
    int* carryA = (int*)(bits3 + NWORDS);                     // 256 KB
    int* carryB = carryA + NWORDS;                            // 256 KB
    int* ncompA = carryB + NWORDS;                            // 64 B
    int* ncompB = ncompA + BATCH;                             // 64 B

    const float4* in4 = (const float4*)in;
    void* args[] = { (void*)&in4, (void*)&out, (void*)&LA, (void*)&sizesA,
                     (void*)&LB, (void*)&sizesB, (void*)&bits1, (void*)&bits2,
                     (void*)&bits3, (void*)&carryA, (void*)&carryB,
                     (void*)&ncompA, (void*)&ncompB };
    hipError_t err = hipLaunchCooperativeKernel((const void*)k_mega, dim3(NSTRIPS),
                                                dim3(256), (void**)args, 0, stream);
    if (err != hipSuccess) {
        (void)hipGetLastError();        // clear sticky error; run proven path
        k_thresh_pack4<<<(NTOT / 4 + TPB - 1) / TPB, TPB, 0, stream>>>((const float4*)in, bits1);
        k_strip_ccl<<<NSTRIPS, SWORDS, 0, stream>>>(bits1, 0, carryA, LA, sizesA, ncompA);
        k_merge_bound<<<BATCH, 256, 0, stream>>>(bits1, 0, carryA, LA);
        k_flatten_count<<<NBLKW, TPB, 0, stream>>>(bits1, 0, carryA, LA, sizesA, ncompA);
        k_keep_strip<<<NSTRIPS, SWORDS, 0, stream>>>(bits1, carryA, LA, sizesA, ncompA,
                                                     bits2, carryB, LB, sizesB, ncompB);
        k_merge_bound<<<BATCH, 256, 0, stream>>>(bits2, 1, carryB, LB);
        k_flatten_count<<<NBLKW, TPB, 0, stream>>>(bits2, 1, carryB, LB, sizesB, ncompB);
        k_fill_morph_ccl<<<NSTRIPS, SWORDS, 0, stream>>>(bits2, carryB, LB, sizesB,
                                                         bits3, carryA, LA, sizesA, ncompA);
        k_merge_bound<<<BATCH, 256, 0, stream>>>(bits3, 0, carryA, LA);
        k_flatten_count<<<NBLKW, TPB, 0, stream>>>(bits3, 0, carryA, LA, sizesA, ncompA);
        k_keep_dilate_float<<<BATCH * 64, TPB, 0, stream>>>(bits3, carryA, LA, sizesA, ncompA, out);
    }
}

// Round 2
// 340.560 us; speedup vs baseline: 2.1171x; 2.1171x over previous
//
#include <hip/hip_runtime.h>
#include <hip/hip_cooperative_groups.h>
#include <stdint.h>

namespace cg = cooperative_groups;

#define BATCH 16
#define H 512
#define W 512
#define HW (H * W)
#define NTOT (BATCH * HW)
#define NWORDS (NTOT / 64)      // 65536 packed words, 8 per row, 4096 per image

#define TPB 256
#define NBLKW ((NWORDS + TPB - 1) / TPB)

#define SROWS 16                // CCL strip = 16 rows
#define SWORDS 128              // words per CCL strip
#define SPIX 8192               // pixels per CCL strip
#define NSTRIPS (NWORDS / SWORDS)   // 512 strips (never straddle images)
#define NBOUND (BATCH * 248)        // 3968 strip-boundary words
#define NSUB 8                      // barrier sub-counters (64 arrivals each)

// ---------------------------------------------------------------------------
// Union-find (global): atomicMin keeps parent <= child (monotone) -> acyclic;
// stale plain reads only cost retries. find_root_c path-compresses.
// ---------------------------------------------------------------------------
__device__ __forceinline__ int find_root_c(int* L, int x) {
    int r = x, p = L[r];
    while (p != r) { r = p; p = L[r]; }
    if (L[x] != r) atomicMin(&L[x], r);
    return r;
}

__device__ void merge_uf(int* L, int a, int b) {
    while (true) {
        a = find_root_c(L, a);
        b = find_root_c(L, b);
        if (a == b) return;
        int lo = a < b ? a : b;
        int hi = a < b ? b : a;
        int old = atomicMin(&L[hi], lo);
        if (old == hi) return;
        a = lo; b = old;
    }
}

__device__ __forceinline__ int find_root_lds(int* P, int x) {
    int r = x, p = P[r];
    while (p != r) { r = p; p = P[r]; }
    return r;
}

__device__ void merge_lds(int* P, int a, int b) {
    while (true) {
        a = find_root_lds(P, a);
        b = find_root_lds(P, b);
        if (a == b) return;
        int lo = a < b ? a : b;
        int hi = a < b ? b : a;
        int old = atomicMin(&P[hi], lo);
        if (old == hi) return;
        a = lo; b = old;
    }
}

// start index of the run containing bit i of word m (base = pixel idx of bit0)
__device__ __forceinline__ int start_of(uint64_t m, int i, int cv, int base) {
    uint64_t below = i ? ((~m) & ((1ull << i) - 1)) : 0ull;
    if (below == 0) return (cv >= 0) ? cv : base;
    int hz = 63 - __builtin_clzll(below);
    return base + hz + 1;
}

// remove-small transform of one word (fg comps; pure function of CCL data)
__device__ uint64_t keep_word(const uint64_t* __restrict__ bits,
                              const int* __restrict__ carry, const int* __restrict__ L,
                              const int* __restrict__ sizes, const int* __restrict__ ncomp,
                              int minsz, int gw) {
    uint64_t m = bits[gw];
    uint64_t res = m;
    if (m && ncomp[gw >> 12] > 1) {
        int cv = carry[gw];
        int base = gw << 6;
        while (m) {
            int s = __builtin_ctzll(m);
            uint64_t rest = m >> s;
            uint64_t nr = ~rest;
            int len = nr ? __builtin_ctzll(nr) : (64 - s);
            uint64_t piece = ((len >= 64) ? ~0ull : ((1ull << len) - 1)) << s;
            int start = (s == 0 && cv >= 0) ? cv : (base + s);
            if (sizes[L[start]] < minsz) res &= ~piece;
            m &= ~piece;
        }
    }
    return res;
}

// fill-holes transform of one word (bg comps; needs inv=1 CCL data)
__device__ uint64_t fill_word(const uint64_t* __restrict__ bits,
                              const int* __restrict__ carry, const int* __restrict__ L,
                              const int* __restrict__ sizes, int minsz, int gw) {
    uint64_t fg = bits[gw];
    uint64_t bg = ~fg;
    uint64_t res = fg;
    int cv = carry[gw];
    int base = gw << 6;
    while (bg) {
        int s = __builtin_ctzll(bg);
        uint64_t rest = bg >> s;
        uint64_t nr = ~rest;
        int len = nr ? __builtin_ctzll(nr) : (64 - s);
        uint64_t piece = ((len >= 64) ? ~0ull : ((1ull << len) - 1)) << s;
        int start = (s == 0 && cv >= 0) ? cv : (base + s);
        if (sizes[L[start]] < minsz) res |= piece;
        bg &= ~piece;
    }
    return res;
}

// one morph output word from an LDS window; gyTop = global row of local row 0
template <int R, bool ERODE>
__device__ uint64_t morph_word_lds(const uint64_t* buf, int lrow, int w, int gyTop) {
    const uint64_t BORDER = ERODE ? ~0ull : 0ull;
    uint64_t res = ERODE ? ~0ull : 0ull;
#pragma unroll
    for (int dy = -R; dy <= R; ++dy) {
        int lr = lrow + dy;
        int gy = gyTop + lr;
        if (gy < 0 || gy >= H) continue;       // image border rows = identity
        int v = R * R - dy * dy;
        int kx = 0;
        while ((kx + 1) * (kx + 1) <= v) ++kx;
        uint64_t cur = buf[lr * 8 + w];
        uint64_t prv = (w > 0) ? buf[lr * 8 + w - 1] : BORDER;
        uint64_t nxt = (w < 7) ? buf[lr * 8 + w + 1] : BORDER;
        uint64_t acc = cur;
#pragma unroll
        for (int dx = 1; dx <= kx; ++dx) {
            uint64_t right = (cur >> dx) | (nxt << (64 - dx));
            uint64_t left  = (cur << dx) | (prv >> (64 - dx));
            if (ERODE) acc &= right & left;
            else       acc |= right | left;
        }
        if (ERODE) res &= acc;
        else       res |= acc;
    }
    return res;
}

// ---------------------------------------------------------------------------
// Strip-local CCL body (guarded: valid for blockDim 128 OR 256; threads with
// t >= SWORDS must pass m = 0 and just participate in the barriers).
// ---------------------------------------------------------------------------
__device__ void strip_ccl_body(uint64_t m, uint64_t* sw, int* scarry, int* par,
                               int blk, int t,
                               int* __restrict__ carry, int* __restrict__ L,
                               int* __restrict__ sizes, int* __restrict__ ncomp) {
    if (t < SWORDS) sw[t] = m;
    __syncthreads();

    if (t < SROWS) {                    // per-row carries
        int cv = -1;
        for (int i = 0; i < 8; ++i) {
            int lw = t * 8 + i;
            scarry[lw] = cv;
            uint64_t w = sw[lw];
            if (w >> 63) {
                uint64_t z = ~w;
                if (z == 0) { if (cv < 0) cv = lw << 6; }
                else { int hz = 63 - __builtin_clzll(z); cv = (lw << 6) + hz + 1; }
            } else cv = -1;
        }
    }
    __syncthreads();

    int lbase = t << 6;
    int cv = -1;
    uint64_t starts = 0ull;
    if (t < SWORDS) {
        cv = scarry[t];
        carry[blk * SWORDS + t] = (cv >= 0) ? (blk * SPIX + cv) : -1;
        starts = m & ~((m << 1) | ((cv >= 0) ? 1ull : 0ull));
        uint64_t ss = starts;
        while (ss) {
            int s = __builtin_ctzll(ss);
            par[lbase + s] = lbase + s;
            ss &= ss - 1;
        }
    }
    __syncthreads();

    if (t >= 8 && t < SWORDS && m) {    // intra-strip vertical unions
        uint64_t up = sw[t - 8];
        uint64_t cand = m & up;
        if (cand) {
            uint64_t curprev = (t & 7) ? sw[t - 1] : 0ull;
            uint64_t upprev  = (t & 7) ? sw[t - 9] : 0ull;
            uint64_t curl = (m << 1) | (curprev >> 63);
            uint64_t upl  = (up << 1) | (upprev >> 63);
            cand &= ~(curl & upl);
            int cvu = scarry[t - 8];
            while (cand) {
                int i = __builtin_ctzll(cand);
                int sP = start_of(m, i, cv, lbase);
                int sQ = start_of(up, i, cvu, lbase - 512);
                merge_lds(par, sP, sQ);
                cand &= cand - 1;
            }
        }
    }
    __syncthreads();

    if (t < SWORDS) {                   // publish depth-1 trees
        int gpix = blk * SPIX;
        uint64_t ss = starts;
        while (ss) {
            int s = __builtin_ctzll(ss);
            int ls = lbase + s;
            int r = find_root_lds(par, ls);
            L[gpix + ls] = gpix + r;
            if (r == ls) sizes[gpix + ls] = 0;
            ss &= ss - 1;
        }
    }
    if (t == 0 && (blk & 31) == 0) ncomp[blk >> 5] = 0;   // 32 strips per image
}

// one cross-strip boundary word (y % 16 == 0, y != 0)
__device__ void merge_bound_item(const uint64_t* __restrict__ bits, uint64_t inv64,
                                 const int* __restrict__ carry, int* __restrict__ L,
                                 int gw, int w) {
    uint64_t cur = bits[gw] ^ inv64;
    uint64_t up  = bits[gw - 8] ^ inv64;
    uint64_t cand = cur & up;
    if (!cand) return;
    uint64_t curprev = w ? (bits[gw - 1] ^ inv64) : 0ull;
    uint64_t upprev  = w ? (bits[gw - 9] ^ inv64) : 0ull;
    uint64_t curl = (cur << 1) | (curprev >> 63);
    uint64_t upl  = (up << 1)  | (upprev >> 63);
    cand &= ~(curl & upl);
    if (!cand) return;
    int cvc = carry[gw], cvu = carry[gw - 8];
    int base = gw << 6;
    while (cand) {
        int i = __builtin_ctzll(cand);
        int sP = start_of(cur, i, cvc, base);
        int sQ = start_of(up, i, cvu, base - W);
        merge_uf(L, sP, sQ);
        cand &= cand - 1;
    }
}

// flatten+count for one strip's 128 words (per-block LDS hash)
__device__ void flatten_block(const uint64_t* __restrict__ bits, uint64_t inv64,
                              const int* __restrict__ carry, int* __restrict__ L,
                              int* __restrict__ sizes, int* __restrict__ ncomp,
                              int blk, int t, int* hk, int* hv) {
    if (t < 128) { hk[t] = -1; hv[t] = 0; }
    __syncthreads();
    if (t < SWORDS) {
        int gw = blk * SWORDS + t;
        uint64_t m = bits[gw] ^ inv64;
        if (m) {
            int cv = carry[gw];
            int base = gw << 6;
            while (m) {
                int s = __builtin_ctzll(m);
                uint64_t rest = m >> s;
                uint64_t nr = ~rest;
                int len = nr ? __builtin_ctzll(nr) : (64 - s);
                uint64_t piece = ((len >= 64) ? ~0ull : ((1ull << len) - 1)) << s;
                bool initial = !(s == 0 && cv >= 0);
                int start = initial ? (base + s) : cv;
                int r = find_root_c(L, start);
                if (initial && r == start) atomicAdd(&ncomp[gw >> 12], 1);
                int cnt = __popcll(piece);
                uint32_t h = ((uint32_t)r * 2654435761u) >> 25;
                bool done = false;
                for (int tt = 0; tt < 16; ++tt) {
                    int slot = (h + tt) & 127;
                    int k = hk[slot];
                    if (k == -1) k = atomicCAS(&hk[slot], -1, r);
                    if (k == -1 || k == r) { atomicAdd(&hv[slot], cnt); done = true; break; }
                }
                if (!done) atomicAdd(&sizes[r], cnt);
                m &= ~piece;
            }
        }
    }
    __syncthreads();
    if (t < 128 && hk[t] != -1) atomicAdd(&sizes[hk[t]], hv[t]);
}

// keep + dilate(disk1) + float4 cast for one 8-row segment (256 threads)
__device__ void keep_dilate_seg(const uint64_t* __restrict__ bits,
                                const int* __restrict__ carry, const int* __restrict__ L,
                                const int* __restrict__ sizes, const int* __restrict__ ncomp,
                                float* __restrict__ out,
                                int img, int y0, int t, uint64_t* kb, uint64_t* db) {
    if (t < 80) {
        int lr = t >> 3;
        int w = t & 7;
        int gy = y0 - 1 + lr;
        uint64_t v = 0;
        if (gy >= 0 && gy < H)
            v = keep_word(bits, carry, L, sizes, ncomp, 2000, img * 4096 + gy * 8 + w);
        kb[t] = v;
    }
    __syncthreads();
    if (t < 64) {
        int r = t >> 3, w = t & 7;
        uint64_t cur = kb[(r + 1) * 8 + w];
        uint64_t up  = kb[r * 8 + w];
        uint64_t dn  = kb[(r + 2) * 8 + w];
        uint64_t prv = w ? kb[(r + 1) * 8 + w - 1] : 0ull;
        uint64_t nxt = (w < 7) ? kb[(r + 1) * 8 + w + 1] : 0ull;
        db[t] = cur | up | dn | (cur << 1) | (prv >> 63) | (cur >> 1) | (nxt << 63);
    }
    __syncthreads();

    int q0 = t * 16;                    // 16 consecutive pixels per thread
    uint64_t wd = db[q0 >> 6];
    int sh = q0 & 63;
    float4* o = (float4*)(out + (size_t)img * HW + (size_t)y0 * W + q0);
#pragma unroll
    for (int k = 0; k < 4; ++k) {
        uint32_t nib = (uint32_t)(wd >> (sh + k * 4)) & 0xFu;
        float4 f;
        f.x = (nib & 1u) ? 1.0f : 0.0f;
        f.y = (nib & 2u) ? 1.0f : 0.0f;
        f.z = (nib & 4u) ? 1.0f : 0.0f;
        f.w = (nib & 8u) ? 1.0f : 0.0f;
        o[k] = f;
    }
}

// ---------------------------------------------------------------------------
// Fast hand-rolled grid barrier (replaces cg::grid.sync()'s ~47 us cost).
// Monotone phase counters -> no reset hazard. 8 padded sub-counters take 64
// arrivals each (parallel cachelines); each sub-group's last arriver bumps the
// master; all blocks' thread 0 spin on master with s_sleep backoff.
// Release/acquire __threadfence() reproduces the visibility that kernel
// boundaries provided (agent-scope L2 writeback/invalidate).
// ---------------------------------------------------------------------------
__device__ __forceinline__ void gbar(int* bar, int phase) {
    __syncthreads();
    if (threadIdx.x == 0) {
        __threadfence();                                   // release
        int g = blockIdx.x & (NSUB - 1);
        int prev = atomicAdd(&bar[g * 32], 1);
        if (prev == (NSTRIPS / NSUB) * phase - 1)
            atomicAdd(&bar[NSUB * 32], 1);
        while (__hip_atomic_load(&bar[NSUB * 32], __ATOMIC_RELAXED,
                                 __HIP_MEMORY_SCOPE_AGENT) < NSUB * phase)
            __builtin_amdgcn_s_sleep(1);
        __threadfence();                                   // acquire
    }
    __syncthreads();
}

// ---------------------------------------------------------------------------
// MEGA: whole pipeline, ONE cooperative kernel, 9 custom barriers.
// grid = 512 blocks (one per CCL strip) x 256 threads. Cooperative launch
// keeps the co-residency guarantee; cg::sync itself is never called.
// ---------------------------------------------------------------------------
__global__ __launch_bounds__(256, 2) void k_mega(
        const float4* __restrict__ in4, float* __restrict__ out,
        int* LA, int* sizesA, int* LB, int* sizesB,
        uint64_t* bits1, uint64_t* bits2, uint64_t* bits3,
        int* carryA, int* carryB, int* ncompA, int* ncompB, int* bar) {
    __shared__ uint64_t sw[SWORDS];
    __shared__ int scarry[SWORDS];
    __shared__ union US {
        int par[SPIX];                                     // 32 KB (CCL)
        struct { uint64_t A[320]; uint64_t B[320]; } mo;   // 5 KB (morph)
        struct { int hk[128]; int hv[128]; } ha;           // 1 KB (flatten hash)
        struct { uint64_t kb[80]; uint64_t db[64]; } kd;   // 1.1 KB (out stage)
    } U;
    int blk = blockIdx.x;
    int t = threadIdx.x;

    // P0: threshold + pack, STRIP-LOCAL (block packs its own 128 words) ->
    // no grid barrier needed before P1, only __syncthreads.
#pragma unroll
    for (int it = 0; it < 8; ++it) {
        int q = blk * (SPIX / 4) + it * 256 + t;           // quad index
        float4 v = in4[q];
        uint32_t nib = (v.x > 0.0f ? 1u : 0u) | (v.y > 0.0f ? 2u : 0u) |
                       (v.z > 0.0f ? 4u : 0u) | (v.w > 0.0f ? 8u : 0u);
        uint64_t val = (uint64_t)nib << (4 * (t & 15));
        val |= __shfl_xor(val, 1);
        val |= __shfl_xor(val, 2);
        val |= __shfl_xor(val, 4);
        val |= __shfl_xor(val, 8);
        if ((t & 15) == 0) bits1[q >> 4] = val;
    }
    __syncthreads();

    // P1: CCL1 strip phase (fg of bits1) -> set A
    {
        uint64_t m = (t < SWORDS) ? bits1[blk * SWORDS + t] : 0ull;
        strip_ccl_body(m, sw, scarry, U.par, blk, t, carryA, LA, sizesA, ncompA);
    }
    gbar(bar, 1);

    // P2: cross-strip merges (bits1, fg) — spread 3968 items over all blocks
    if (t < 8) {
        int item = blk * 8 + t;
        if (item < NBOUND) {
            int img = item / 248;
            int r = item - img * 248;
            int gw = img * 4096 + ((r >> 3) + 1) * SROWS * 8 + (r & 7);
            merge_bound_item(bits1, 0ull, carryA, LA, gw, r & 7);
        }
    }
    gbar(bar, 2);

    // P3: flatten + count (bits1, fg) -> sizesA, ncompA
    flatten_block(bits1, 0ull, carryA, LA, sizesA, ncompA, blk, t, U.ha.hk, U.ha.hv);
    gbar(bar, 3);

    // P4: remove_small_objects(2000,guard) -> bits2, fused with CCL2 strip (bg)
    {
        uint64_t m = 0ull;
        if (t < SWORDS) {
            int gw = blk * SWORDS + t;
            uint64_t kw = keep_word(bits1, carryA, LA, sizesA, ncompA, 2000, gw);
            bits2[gw] = kw;
            m = ~kw;
        }
        strip_ccl_body(m, sw, scarry, U.par, blk, t, carryB, LB, sizesB, ncompB);
    }
    gbar(bar, 4);

    // P5: cross-strip merges (bits2, bg)
    if (t < 8) {
        int item = blk * 8 + t;
        if (item < NBOUND) {
            int img = item / 248;
            int r = item - img * 248;
            int gw = img * 4096 + ((r >> 3) + 1) * SROWS * 8 + (r & 7);
            merge_bound_item(bits2, ~0ull, carryB, LB, gw, r & 7);
        }
    }
    gbar(bar, 5);

    // P6: flatten + count (bits2, bg) -> sizesB
    flatten_block(bits2, ~0ull, carryB, LB, sizesB, ncompB, blk, t, U.ha.hk, U.ha.hv);
    gbar(bar, 6);

    // P7: fill_holes(<301) + erode(d2) + opening(d5) + CCL3 strip -> bits3, set A
    {
        int img = blk >> 5, si = blk & 31;
        int gyTop = si * 16 - 12;
        for (int lw = t; lw < 320; lw += 256) {              // load + fill-holes
            int gy = gyTop + (lw >> 3);
            int w = lw & 7;
            uint64_t v = 0;
            if (gy >= 0 && gy < H)
                v = fill_word(bits2, carryB, LB, sizesB, 301, img * 4096 + gy * 8 + w);
            U.mo.A[lw] = v;
        }
        __syncthreads();
        for (int lw = t; lw < 320; lw += 256) {              // erode disk(2)
            int lr = lw >> 3;
            if (lr >= 2 && lr <= 37) U.mo.B[lw] = morph_word_lds<2, true>(U.mo.A, lr, lw & 7, gyTop);
        }
        __syncthreads();
        for (int lw = t; lw < 320; lw += 256) {              // erode disk(5)
            int lr = lw >> 3;
            if (lr >= 7 && lr <= 32) U.mo.A[lw] = morph_word_lds<5, true>(U.mo.B, lr, lw & 7, gyTop);
        }
        __syncthreads();
        for (int lw = t; lw < 320; lw += 256) {              // dilate disk(5)
            int lr = lw >> 3;
            if (lr >= 12 && lr <= 27) U.mo.B[lw] = morph_word_lds<5, false>(U.mo.A, lr, lw & 7, gyTop);
        }
        __syncthreads();
        uint64_t m3 = 0ull;
        if (t < SWORDS) {
            m3 = U.mo.B[t + 96];        // local rows 12..27 = this strip
            bits3[blk * SWORDS + t] = m3;
        }
        // par aliases mo — safe: all mo.B reads (m3) happen before body's first
        // par write, which is behind two __syncthreads
        strip_ccl_body(m3, sw, scarry, U.par, blk, t, carryA, LA, sizesA, ncompA);
    }
    gbar(bar, 7);

    // P8: cross-strip merges (bits3, fg)
    if (t < 8) {
        int item = blk * 8 + t;
        if (item < NBOUND) {
            int img = item / 248;
            int r = item - img * 248;
            int gw = img * 4096 + ((r >> 3) + 1) * SROWS * 8 + (r & 7);
            merge_bound_item(bits3, 0ull, carryA, LA, gw, r & 7);
        }
    }
    gbar(bar, 8);

    // P9: flatten + count (bits3, fg) -> sizesA, ncompA
    flatten_block(bits3, 0ull, carryA, LA, sizesA, ncompA, blk, t, U.ha.hk, U.ha.hv);
    gbar(bar, 9);

    // P10: remove_small_objects(2000,guard) + dilate(d1) + float4 out
    // 1024 8-row segments -> 2 per block
    for (int k = 0; k < 2; ++k) {
        int seg = blk * 2 + k;
        int img = seg >> 6, s8 = seg & 63;
        keep_dilate_seg(bits3, carryA, LA, sizesA, ncompA, out,
                        img, s8 * 8, t, U.kd.kb, U.kd.db);
        __syncthreads();
    }
}

// ---------------------------------------------------------------------------
// Legacy kernels (fallback path — identical to the proven 11-dispatch version)
// ---------------------------------------------------------------------------
__global__ void k_thresh_pack4(const float4* __restrict__ in4,
                               uint64_t* __restrict__ bits) {
    int q = blockIdx.x * blockDim.x + threadIdx.x;    // quad index (4 px)
    if (q >= NTOT / 4) return;
    float4 v = in4[q];
    uint32_t nib = (v.x > 0.0f ? 1u : 0u) | (v.y > 0.0f ? 2u : 0u) |
                   (v.z > 0.0f ? 4u : 0u) | (v.w > 0.0f ? 8u : 0u);
    uint64_t val = (uint64_t)nib << (4 * (threadIdx.x & 15));
    val |= __shfl_xor(val, 1);
    val |= __shfl_xor(val, 2);
    val |= __shfl_xor(val, 4);
    val |= __shfl_xor(val, 8);
    if ((threadIdx.x & 15) == 0) bits[q >> 4] = val;
}

__global__ void k_strip_ccl(const uint64_t* __restrict__ bits, int inv,
                            int* __restrict__ carry, int* __restrict__ L,
                            int* __restrict__ sizes, int* __restrict__ ncomp) {
    __shared__ uint64_t sw[SWORDS];
    __shared__ int scarry[SWORDS];
    __shared__ int par[SPIX];
    int blk = blockIdx.x;
    int t = threadIdx.x;
    uint64_t inv64 = inv ? ~0ull : 0ull;
    uint64_t m = bits[blk * SWORDS + t] ^ inv64;
    strip_ccl_body(m, sw, scarry, par, blk, t, carry, L, sizes, ncomp);
}

__global__ void k_keep_strip(const uint64_t* __restrict__ bits,
                             const int* __restrict__ carryIn, const int* __restrict__ Lin,
                             const int* __restrict__ sizesIn, const int* __restrict__ ncompIn,
                             uint64_t* __restrict__ outBits,
                             int* __restrict__ carryOut, int* __restrict__ Lout,
                             int* __restrict__ sizesOut, int* __restrict__ ncompOut) {
    __shared__ uint64_t sw[SWORDS];
    __shared__ int scarry[SWORDS];
    __shared__ int par[SPIX];
    int blk = blockIdx.x;
    int t = threadIdx.x;
    int gw = blk * SWORDS + t;
    uint64_t kw = keep_word(bits, carryIn, Lin, sizesIn, ncompIn, 2000, gw);
    outBits[gw] = kw;
    strip_ccl_body(~kw, sw, scarry, par, blk, t, carryOut, Lout, sizesOut, ncompOut);
}

__global__ void k_merge_bound(const uint64_t* __restrict__ bits, int inv,
                              const int* __restrict__ carry, int* __restrict__ L) {
    int tid = threadIdx.x;
    if (tid >= 248) return;             // 31 boundary rows x 8 words
    int img = blockIdx.x;
    int y = ((tid >> 3) + 1) * SROWS;
    int w = tid & 7;
    int gw = img * 4096 + y * 8 + w;
    uint64_t inv64 = inv ? ~0ull : 0ull;
    merge_bound_item(bits, inv64, carry, L, gw, w);
}

__global__ void k_flatten_count(const uint64_t* __restrict__ bits, int inv,
                                const int* __restrict__ carry, int* __restrict__ L,
                                int* __restrict__ sizes, int* __restrict__ ncomp) {
    __shared__ int hk[128];
    __shared__ int hv[128];
    for (int i = threadIdx.x; i < 128; i += TPB) { hk[i] = -1; hv[i] = 0; }
    __syncthreads();

    int gw = blockIdx.x * blockDim.x + threadIdx.x;
    if (gw < NWORDS) {
        uint64_t inv64 = inv ? ~0ull : 0ull;
        uint64_t m = bits[gw] ^ inv64;
        if (m) {
            int cv = carry[gw];
            int base = gw << 6;
            while (m) {
                int s = __builtin_ctzll(m);
                uint64_t rest = m >> s;
                uint64_t nr = ~rest;
                int len = nr ? __builtin_ctzll(nr) : (64 - s);
                uint64_t piece = ((len >= 64) ? ~0ull : ((1ull << len) - 1)) << s;
                bool initial = !(s == 0 && cv >= 0);
                int start = initial ? (base + s) : cv;
                int r = find_root_c(L, start);
                if (initial && r == start) atomicAdd(&ncomp[gw >> 12], 1);
                int cnt = __popcll(piece);
                uint32_t h = ((uint32_t)r * 2654435761u) >> 25;
                bool done = false;
                for (int tt = 0; tt < 16; ++tt) {
                    int slot = (h + tt) & 127;
                    int k = hk[slot];
                    if (k == -1) k = atomicCAS(&hk[slot], -1, r);
                    if (k == -1 || k == r) { atomicAdd(&hv[slot], cnt); done = true; break; }
                }
                if (!done) atomicAdd(&sizes[r], cnt);
                m &= ~piece;
            }
        }
    }
    __syncthreads();
    for (int i = threadIdx.x; i < 128; i += TPB)
        if (hk[i] != -1) atomicAdd(&sizes[hk[i]], hv[i]);
}

__global__ void k_fill_morph_ccl(const uint64_t* __restrict__ bits,
                                 const int* __restrict__ carryB, const int* __restrict__ LB,
                                 const int* __restrict__ sizesB,
                                 uint64_t* __restrict__ bits3,
                                 int* __restrict__ carryA, int* __restrict__ LA,
                                 int* __restrict__ sizesA, int* __restrict__ ncompA) {
    __shared__ uint64_t sw[SWORDS];
    __shared__ int scarry[SWORDS];
    __shared__ union {
        int par[SPIX];                                     // 32 KB (CCL)
        struct { uint64_t A[320]; uint64_t B[320]; } mo;   // 5 KB (morph)
    } U;
    int s = blockIdx.x;                 // strip id (32 per image)
    int t = threadIdx.x;
    int img = s >> 5, si = s & 31;
    int gyTop = si * 16 - 12;

    for (int lw = t; lw < 320; lw += SWORDS) {   // load + fill-holes
        int gy = gyTop + (lw >> 3);
        int w = lw & 7;
        uint64_t v = 0;
        if (gy >= 0 && gy < H)
            v = fill_word(bits, carryB, LB, sizesB, 301, img * 4096 + gy * 8 + w);
        U.mo.A[lw] = v;
    }
    __syncthreads();
    for (int lw = t; lw < 320; lw += SWORDS) {   // erode disk(2): rows 2..37
        int lr = lw >> 3;
        if (lr >= 2 && lr <= 37) U.mo.B[lw] = morph_word_lds<2, true>(U.mo.A, lr, lw & 7, gyTop);
    }
    __syncthreads();
    for (int lw = t; lw < 320; lw += SWORDS) {   // erode disk(5): rows 7..32
        int lr = lw >> 3;
        if (lr >= 7 && lr <= 32) U.mo.A[lw] = morph_word_lds<5, true>(U.mo.B, lr, lw & 7, gyTop);
    }
    __syncthreads();
    for (int lw = t; lw < 320; lw += SWORDS) {   // dilate disk(5): rows 12..27
        int lr = lw >> 3;
        if (lr >= 12 && lr <= 27) U.mo.B[lw] = morph_word_lds<5, false>(U.mo.A, lr, lw & 7, gyTop);
    }
    __syncthreads();
    uint64_t m3 = U.mo.B[t + 96];       // local rows 12..27 = this strip
    bits3[s * SWORDS + t] = m3;
    strip_ccl_body(m3, sw, scarry, U.par, s, t, carryA, LA, sizesA, ncompA);
}

__global__ void k_keep_dilate_float(const uint64_t* __restrict__ bits,
                                    const int* __restrict__ carry, const int* __restrict__ L,
                                    const int* __restrict__ sizes, const int* __restrict__ ncomp,
                                    float* __restrict__ out) {
    __shared__ uint64_t kb[10 * 8];     // rows y0-1 .. y0+8
    __shared__ uint64_t db[8 * 8];      // dilated output rows
    int blk = blockIdx.x;
    int img = blk >> 6;                 // 64 blocks per image
    int s = blk & 63;
    keep_dilate_seg(bits, carry, L, sizes, ncomp, out, img, s * 8, threadIdx.x, kb, db);
}

// ---------------------------------------------------------------------------
// Host side — memset(bar) + 1 cooperative dispatch (fallback: 11 dispatches)
// ---------------------------------------------------------------------------
extern "C" void kernel_launch(void* const* d_in, const int* in_sizes, int n_in,
                              void* d_out, int out_size, void* d_ws, size_t ws_size,
                              hipStream_t stream) {
    const float* in = (const float*)d_in[0];
    float* out = (float*)d_out;

    uint8_t* ws = (uint8_t*)d_ws;
    int* LA      = (int*)ws;                                  // 16 MB
    int* sizesA  = (int*)(ws + (size_t)NTOT * 4);             // 16 MB
    int* LB      = (int*)(ws + (size_t)NTOT * 8);             // 16 MB
    int* sizesB  = (int*)(ws + (size_t)NTOT * 12);            // 16 MB
    uint64_t* bits1 = (uint64_t*)(ws + (size_t)NTOT * 16);    // 512 KB
    uint64_t* bits2 = bits1 + NWORDS;                         // 512 KB
    uint64_t* bits3 = bits2 + NWORDS;                         // 512 KB
    int* carryA = (int*)(bits3 + NWORDS);                     // 256 KB
    int* carryB = carryA + NWORDS;                            // 256 KB
    int* ncompA = carryB + NWORDS;                            // 64 B
    int* ncompB = ncompA + BATCH;                             // 64 B
    int* bar    = ncompB + BATCH;                             // 1.1 KB barrier counters

    hipMemsetAsync(bar, 0, (NSUB * 32 + 32) * sizeof(int), stream);

    const float4* in4 = (const float4*)in;
    void* args[] = { (void*)&in4, (void*)&out, (void*)&LA, (void*)&sizesA,
                     (void*)&LB, (void*)&sizesB, (void*)&bits1, (void*)&bits2,
                     (void*)&bits3, (void*)&carryA, (void*)&carryB,
                     (void*)&ncompA, (void*)&ncompB, (void*)&bar };
    hipError_t err = hipLaunchCooperativeKernel((const void*)k_mega, dim3(NSTRIPS),
                                                dim3(256), (void**)args, 0, stream);
    if (err != hipSuccess) {
        (void)hipGetLastError();        // clear sticky error; run proven path
        k_thresh_pack4<<<(NTOT / 4 + TPB - 1) / TPB, TPB, 0, stream>>>((const float4*)in, bits1);
        k_strip_ccl<<<NSTRIPS, SWORDS, 0, stream>>>(bits1, 0, carryA, LA, sizesA, ncompA);
        k_merge_bound<<<BATCH, 256, 0, stream>>>(bits1, 0, carryA, LA);
        k_flatten_count<<<NBLKW, TPB, 0, stream>>>(bits1, 0, carryA, LA, sizesA, ncompA);
        k_keep_strip<<<NSTRIPS, SWORDS, 0, stream>>>(bits1, carryA, LA, sizesA, ncompA,
                                                     bits2, carryB, LB, sizesB, ncompB);
        k_merge_bound<<<BATCH, 256, 0, stream>>>(bits2, 1, carryB, LB);
        k_flatten_count<<<NBLKW, TPB, 0, stream>>>(bits2, 1, carryB, LB, sizesB, ncompB);
        k_fill_morph_ccl<<<NSTRIPS, SWORDS, 0, stream>>>(bits2, carryB, LB, sizesB,
                                                         bits3, carryA, LA, sizesA, ncompA);
        k_merge_bound<<<BATCH, 256, 0, stream>>>(bits3, 0, carryA, LA);
        k_flatten_count<<<NBLKW, TPB, 0, stream>>>(bits3, 0, carryA, LA, sizesA, ncompA);
        k_keep_dilate_float<<<BATCH * 64, TPB, 0, stream>>>(bits3, carryA, LA, sizesA, ncompA, out);
    }
}

// Round 3
// 320.415 us; speedup vs baseline: 2.2503x; 1.0629x over previous
//
#include <hip/hip_runtime.h>
#include <stdint.h>

#define BATCH 16
#define H 512
#define W 512
#define HW (H * W)
#define NTOT (BATCH * HW)
#define NWORDS (NTOT / 64)      // 65536 packed words, 8 per row, 4096 per image

#define SROWS 16                // CCL strip = 16 rows
#define SWORDS 128              // words per CCL strip
#define SPIX 8192               // pixels per CCL strip
#define NSTRIPS (NWORDS / SWORDS)   // 512 strips (never straddle images)
#define NBOUND (BATCH * 248)        // 3968 strip-boundary words

#define FLAG_STRIDE 16              // 64 B per flag line
#define SPIN_LIMIT (1 << 20)        // hang-insurance: ~0.5 s then give up loudly

// ---------------------------------------------------------------------------
// Union-find (global): atomicMin keeps parent <= child (monotone) -> acyclic;
// stale plain reads only cost retries. find_root_c path-compresses.
// ---------------------------------------------------------------------------
__device__ __forceinline__ int find_root_c(int* L, int x) {
    int r = x, p = L[r];
    while (p != r) { r = p; p = L[r]; }
    if (L[x] != r) atomicMin(&L[x], r);
    return r;
}

__device__ void merge_uf(int* L, int a, int b) {
    while (true) {
        a = find_root_c(L, a);
        b = find_root_c(L, b);
        if (a == b) return;
        int lo = a < b ? a : b;
        int hi = a < b ? b : a;
        int old = atomicMin(&L[hi], lo);
        if (old == hi) return;
        a = lo; b = old;
    }
}

__device__ __forceinline__ int find_root_lds(int* P, int x) {
    int r = x, p = P[r];
    while (p != r) { r = p; p = P[r]; }
    return r;
}

__device__ void merge_lds(int* P, int a, int b) {
    while (true) {
        a = find_root_lds(P, a);
        b = find_root_lds(P, b);
        if (a == b) return;
        int lo = a < b ? a : b;
        int hi = a < b ? b : a;
        int old = atomicMin(&P[hi], lo);
        if (old == hi) return;
        a = lo; b = old;
    }
}

// start index of the run containing bit i of word m (base = pixel idx of bit0)
__device__ __forceinline__ int start_of(uint64_t m, int i, int cv, int base) {
    uint64_t below = i ? ((~m) & ((1ull << i) - 1)) : 0ull;
    if (below == 0) return (cv >= 0) ? cv : base;
    int hz = 63 - __builtin_clzll(below);
    return base + hz + 1;
}

// remove-small transform of one word (fg comps; pure function of CCL data)
__device__ uint64_t keep_word(const uint64_t* __restrict__ bits,
                              const int* __restrict__ carry, const int* __restrict__ L,
                              const int* __restrict__ sizes, const int* __restrict__ ncomp,
                              int minsz, int gw) {
    uint64_t m = bits[gw];
    uint64_t res = m;
    if (m && ncomp[gw >> 12] > 1) {
        int cv = carry[gw];
        int base = gw << 6;
        while (m) {
            int s = __builtin_ctzll(m);
            uint64_t rest = m >> s;
            uint64_t nr = ~rest;
            int len = nr ? __builtin_ctzll(nr) : (64 - s);
            uint64_t piece = ((len >= 64) ? ~0ull : ((1ull << len) - 1)) << s;
            int start = (s == 0 && cv >= 0) ? cv : (base + s);
            if (sizes[L[start]] < minsz) res &= ~piece;
            m &= ~piece;
        }
    }
    return res;
}

// fill-holes transform of one word (bg comps; needs inv=1 CCL data)
__device__ uint64_t fill_word(const uint64_t* __restrict__ bits,
                              const int* __restrict__ carry, const int* __restrict__ L,
                              const int* __restrict__ sizes, int minsz, int gw) {
    uint64_t fg = bits[gw];
    uint64_t bg = ~fg;
    uint64_t res = fg;
    int cv = carry[gw];
    int base = gw << 6;
    while (bg) {
        int s = __builtin_ctzll(bg);
        uint64_t rest = bg >> s;
        uint64_t nr = ~rest;
        int len = nr ? __builtin_ctzll(nr) : (64 - s);
        uint64_t piece = ((len >= 64) ? ~0ull : ((1ull << len) - 1)) << s;
        int start = (s == 0 && cv >= 0) ? cv : (base + s);
        if (sizes[L[start]] < minsz) res |= piece;
        bg &= ~piece;
    }
    return res;
}

// one morph output word from an LDS window; gyTop = global row of local row 0
template <int R, bool ERODE>
__device__ uint64_t morph_word_lds(const uint64_t* buf, int lrow, int w, int gyTop) {
    const uint64_t BORDER = ERODE ? ~0ull : 0ull;
    uint64_t res = ERODE ? ~0ull : 0ull;
#pragma unroll
    for (int dy = -R; dy <= R; ++dy) {
        int lr = lrow + dy;
        int gy = gyTop + lr;
        if (gy < 0 || gy >= H) continue;       // image border rows = identity
        int v = R * R - dy * dy;
        int kx = 0;
        while ((kx + 1) * (kx + 1) <= v) ++kx;
        uint64_t cur = buf[lr * 8 + w];
        uint64_t prv = (w > 0) ? buf[lr * 8 + w - 1] : BORDER;
        uint64_t nxt = (w < 7) ? buf[lr * 8 + w + 1] : BORDER;
        uint64_t acc = cur;
#pragma unroll
        for (int dx = 1; dx <= kx; ++dx) {
            uint64_t right = (cur >> dx) | (nxt << (64 - dx));
            uint64_t left  = (cur << dx) | (prv >> (64 - dx));
            if (ERODE) acc &= right & left;
            else       acc |= right | left;
        }
        if (ERODE) res &= acc;
        else       res |= acc;
    }
    return res;
}

// ---------------------------------------------------------------------------
// Strip-local CCL body (guarded: valid for blockDim 128 OR 256; threads with
// t >= SWORDS must pass m = 0 and just participate in the barriers).
// ---------------------------------------------------------------------------
__device__ void strip_ccl_body(uint64_t m, uint64_t* sw, int* scarry, int* par,
                               int blk, int t,
                               int* __restrict__ carry, int* __restrict__ L,
                               int* __restrict__ sizes, int* __restrict__ ncomp) {
    if (t < SWORDS) sw[t] = m;
    __syncthreads();

    if (t < SROWS) {                    // per-row carries
        int cv = -1;
        for (int i = 0; i < 8; ++i) {
            int lw = t * 8 + i;
            scarry[lw] = cv;
            uint64_t w = sw[lw];
            if (w >> 63) {
                uint64_t z = ~w;
                if (z == 0) { if (cv < 0) cv = lw << 6; }
                else { int hz = 63 - __builtin_clzll(z); cv = (lw << 6) + hz + 1; }
            } else cv = -1;
        }
    }
    __syncthreads();

    int lbase = t << 6;
    int cv = -1;
    uint64_t starts = 0ull;
    if (t < SWORDS) {
        cv = scarry[t];
        carry[blk * SWORDS + t] = (cv >= 0) ? (blk * SPIX + cv) : -1;
        starts = m & ~((m << 1) | ((cv >= 0) ? 1ull : 0ull));
        uint64_t ss = starts;
        while (ss) {
            int s = __builtin_ctzll(ss);
            par[lbase + s] = lbase + s;
            ss &= ss - 1;
        }
    }
    __syncthreads();

    if (t >= 8 && t < SWORDS && m) {    // intra-strip vertical unions
        uint64_t up = sw[t - 8];
        uint64_t cand = m & up;
        if (cand) {
            uint64_t curprev = (t & 7) ? sw[t - 1] : 0ull;
            uint64_t upprev  = (t & 7) ? sw[t - 9] : 0ull;
            uint64_t curl = (m << 1) | (curprev >> 63);
            uint64_t upl  = (up << 1) | (upprev >> 63);
            cand &= ~(curl & upl);
            int cvu = scarry[t - 8];
            while (cand) {
                int i = __builtin_ctzll(cand);
                int sP = start_of(m, i, cv, lbase);
                int sQ = start_of(up, i, cvu, lbase - 512);
                merge_lds(par, sP, sQ);
                cand &= cand - 1;
            }
        }
    }
    __syncthreads();

    if (t < SWORDS) {                   // publish depth-1 trees
        int gpix = blk * SPIX;
        uint64_t ss = starts;
        while (ss) {
            int s = __builtin_ctzll(ss);
            int ls = lbase + s;
            int r = find_root_lds(par, ls);
            L[gpix + ls] = gpix + r;
            if (r == ls) sizes[gpix + ls] = 0;
            ss &= ss - 1;
        }
    }
    if (t == 0 && (blk & 31) == 0) ncomp[blk >> 5] = 0;   // 32 strips per image
}

// one cross-strip boundary word (y % 16 == 0, y != 0)
__device__ void merge_bound_item(const uint64_t* __restrict__ bits, uint64_t inv64,
                                 const int* __restrict__ carry, int* __restrict__ L,
                                 int gw, int w) {
    uint64_t cur = bits[gw] ^ inv64;
    uint64_t up  = bits[gw - 8] ^ inv64;
    uint64_t cand = cur & up;
    if (!cand) return;
    uint64_t curprev = w ? (bits[gw - 1] ^ inv64) : 0ull;
    uint64_t upprev  = w ? (bits[gw - 9] ^ inv64) : 0ull;
    uint64_t curl = (cur << 1) | (curprev >> 63);
    uint64_t upl  = (up << 1)  | (upprev >> 63);
    cand &= ~(curl & upl);
    if (!cand) return;
    int cvc = carry[gw], cvu = carry[gw - 8];
    int base = gw << 6;
    while (cand) {
        int i = __builtin_ctzll(cand);
        int sP = start_of(cur, i, cvc, base);
        int sQ = start_of(up, i, cvu, base - W);
        merge_uf(L, sP, sQ);
        cand &= cand - 1;
    }
}

// flatten+count for one strip's 128 words (per-block LDS hash)
__device__ void flatten_block(const uint64_t* __restrict__ bits, uint64_t inv64,
                              const int* __restrict__ carry, int* __restrict__ L,
                              int* __restrict__ sizes, int* __restrict__ ncomp,
                              int blk, int t, int* hk, int* hv) {
    if (t < 128) { hk[t] = -1; hv[t] = 0; }
    __syncthreads();
    if (t < SWORDS) {
        int gw = blk * SWORDS + t;
        uint64_t m = bits[gw] ^ inv64;
        if (m) {
            int cv = carry[gw];
            int base = gw << 6;
            while (m) {
                int s = __builtin_ctzll(m);
                uint64_t rest = m >> s;
                uint64_t nr = ~rest;
                int len = nr ? __builtin_ctzll(nr) : (64 - s);
                uint64_t piece = ((len >= 64) ? ~0ull : ((1ull << len) - 1)) << s;
                bool initial = !(s == 0 && cv >= 0);
                int start = initial ? (base + s) : cv;
                int r = find_root_c(L, start);
                if (initial && r == start) atomicAdd(&ncomp[gw >> 12], 1);
                int cnt = __popcll(piece);
                uint32_t h = ((uint32_t)r * 2654435761u) >> 25;
                bool done = false;
                for (int tt = 0; tt < 16; ++tt) {
                    int slot = (h + tt) & 127;
                    int k = hk[slot];
                    if (k == -1) k = atomicCAS(&hk[slot], -1, r);
                    if (k == -1 || k == r) { atomicAdd(&hv[slot], cnt); done = true; break; }
                }
                if (!done) atomicAdd(&sizes[r], cnt);
                m &= ~piece;
            }
        }
    }
    __syncthreads();
    if (t < 128 && hk[t] != -1) atomicAdd(&sizes[hk[t]], hv[t]);
}

// keep + dilate(disk1) + float4 cast for one 8-row segment (256 threads)
__device__ void keep_dilate_seg(const uint64_t* __restrict__ bits,
                                const int* __restrict__ carry, const int* __restrict__ L,
                                const int* __restrict__ sizes, const int* __restrict__ ncomp,
                                float* __restrict__ out,
                                int img, int y0, int t, uint64_t* kb, uint64_t* db) {
    if (t < 80) {
        int lr = t >> 3;
        int w = t & 7;
        int gy = y0 - 1 + lr;
        uint64_t v = 0;
        if (gy >= 0 && gy < H)
            v = keep_word(bits, carry, L, sizes, ncomp, 2000, img * 4096 + gy * 8 + w);
        kb[t] = v;
    }
    __syncthreads();
    if (t < 64) {
        int r = t >> 3, w = t & 7;
        uint64_t cur = kb[(r + 1) * 8 + w];
        uint64_t up  = kb[r * 8 + w];
        uint64_t dn  = kb[(r + 2) * 8 + w];
        uint64_t prv = w ? kb[(r + 1) * 8 + w - 1] : 0ull;
        uint64_t nxt = (w < 7) ? kb[(r + 1) * 8 + w + 1] : 0ull;
        db[t] = cur | up | dn | (cur << 1) | (prv >> 63) | (cur >> 1) | (nxt << 63);
    }
    __syncthreads();

    int q0 = t * 16;                    // 16 consecutive pixels per thread
    uint64_t wd = db[q0 >> 6];
    int sh = q0 & 63;
    float4* o = (float4*)(out + (size_t)img * HW + (size_t)y0 * W + q0);
#pragma unroll
    for (int k = 0; k < 4; ++k) {
        uint32_t nib = (uint32_t)(wd >> (sh + k * 4)) & 0xFu;
        float4 f;
        f.x = (nib & 1u) ? 1.0f : 0.0f;
        f.y = (nib & 2u) ? 1.0f : 0.0f;
        f.z = (nib & 4u) ? 1.0f : 0.0f;
        f.w = (nib & 8u) ? 1.0f : 0.0f;
        o[k] = f;
    }
}

// ---------------------------------------------------------------------------
// O(1)-contention grid barrier. Round-2 post-mortem: 64 serialized atomicAdds
// per sub-counter line = ~26 us/barrier. Here arrival is contention-free:
// each block store-releases its OWN padded flag; block 0's 256 threads poll
// all 512 flags in parallel, then publish `go`; everyone polls go.
// Spin loops carry an iteration cap so a (theoretically impossible) residency
// failure shows up as a wrong answer, not a device hang.
// ---------------------------------------------------------------------------
__device__ __forceinline__ void gbar(int* flags, int phase) {
    int* go = flags + NSTRIPS * FLAG_STRIDE;
    __syncthreads();
    if (threadIdx.x == 0) {
        __threadfence();                                   // release our writes
        __hip_atomic_store(&flags[blockIdx.x * FLAG_STRIDE], phase,
                           __ATOMIC_RELAXED, __HIP_MEMORY_SCOPE_AGENT);
    }
    if (blockIdx.x == 0) {
        int spins = 0;
        while (__hip_atomic_load(&flags[threadIdx.x * FLAG_STRIDE],
                                 __ATOMIC_RELAXED, __HIP_MEMORY_SCOPE_AGENT) < phase
               && ++spins < SPIN_LIMIT)
            __builtin_amdgcn_s_sleep(1);
        while (__hip_atomic_load(&flags[(threadIdx.x + 256) * FLAG_STRIDE],
                                 __ATOMIC_RELAXED, __HIP_MEMORY_SCOPE_AGENT) < phase
               && ++spins < SPIN_LIMIT)
            __builtin_amdgcn_s_sleep(1);
        __syncthreads();
        if (threadIdx.x == 0) {
            __threadfence();
            __hip_atomic_store(go, phase, __ATOMIC_RELAXED,
                               __HIP_MEMORY_SCOPE_AGENT);
        }
    }
    if (threadIdx.x == 0) {
        int spins = 0;
        while (__hip_atomic_load(go, __ATOMIC_RELAXED,
                                 __HIP_MEMORY_SCOPE_AGENT) < phase
               && ++spins < SPIN_LIMIT)
            __builtin_amdgcn_s_sleep(1);
        __threadfence();                                   // acquire others' writes
    }
    __syncthreads();
}

// ---------------------------------------------------------------------------
// MEGA: whole pipeline, ONE regular kernel, 9 flag barriers.
// 512 blocks x 256 thr, 52 VGPR, 34.3 KB LDS -> 2 blocks/CU by launch bounds
// (LDS alone would allow 4): all 512 blocks co-resident on 256 CUs under a
// plain launch, so no cooperative launch (round-2 showed ~75 us overhead).
// ---------------------------------------------------------------------------
__global__ __launch_bounds__(256, 2) void k_mega(
        const float4* __restrict__ in4, float* __restrict__ out,
        int* LA, int* sizesA, int* LB, int* sizesB,
        uint64_t* bits1, uint64_t* bits2, uint64_t* bits3,
        int* carryA, int* carryB, int* ncompA, int* ncompB, int* flags) {
    __shared__ uint64_t sw[SWORDS];
    __shared__ int scarry[SWORDS];
    __shared__ union US {
        int par[SPIX];                                     // 32 KB (CCL)
        struct { uint64_t A[320]; uint64_t B[320]; } mo;   // 5 KB (morph)
        struct { int hk[128]; int hv[128]; } ha;           // 1 KB (flatten hash)
        struct { uint64_t kb[80]; uint64_t db[64]; } kd;   // 1.1 KB (out stage)
    } U;
    int blk = blockIdx.x;
    int t = threadIdx.x;

    // P0: threshold + pack, STRIP-LOCAL (block packs its own 128 words) ->
    // no grid barrier needed before P1, only __syncthreads.
#pragma unroll
    for (int it = 0; it < 8; ++it) {
        int q = blk * (SPIX / 4) + it * 256 + t;           // quad index
        float4 v = in4[q];
        uint32_t nib = (v.x > 0.0f ? 1u : 0u) | (v.y > 0.0f ? 2u : 0u) |
                       (v.z > 0.0f ? 4u : 0u) | (v.w > 0.0f ? 8u : 0u);
        uint64_t val = (uint64_t)nib << (4 * (t & 15));
        val |= __shfl_xor(val, 1);
        val |= __shfl_xor(val, 2);
        val |= __shfl_xor(val, 4);
        val |= __shfl_xor(val, 8);
        if ((t & 15) == 0) bits1[q >> 4] = val;
    }
    __syncthreads();

    // P1: CCL1 strip phase (fg of bits1) -> set A
    {
        uint64_t m = (t < SWORDS) ? bits1[blk * SWORDS + t] : 0ull;
        strip_ccl_body(m, sw, scarry, U.par, blk, t, carryA, LA, sizesA, ncompA);
    }
    gbar(flags, 1);

    // P2: cross-strip merges (bits1, fg) — spread 3968 items over all blocks
    if (t < 8) {
        int item = blk * 8 + t;
        if (item < NBOUND) {
            int img = item / 248;
            int r = item - img * 248;
            int gw = img * 4096 + ((r >> 3) + 1) * SROWS * 8 + (r & 7);
            merge_bound_item(bits1, 0ull, carryA, LA, gw, r & 7);
        }
    }
    gbar(flags, 2);

    // P3: flatten + count (bits1, fg) -> sizesA, ncompA
    flatten_block(bits1, 0ull, carryA, LA, sizesA, ncompA, blk, t, U.ha.hk, U.ha.hv);
    gbar(flags, 3);

    // P4: remove_small_objects(2000,guard) -> bits2, fused with CCL2 strip (bg)
    {
        uint64_t m = 0ull;
        if (t < SWORDS) {
            int gw = blk * SWORDS + t;
            uint64_t kw = keep_word(bits1, carryA, LA, sizesA, ncompA, 2000, gw);
            bits2[gw] = kw;
            m = ~kw;
        }
        strip_ccl_body(m, sw, scarry, U.par, blk, t, carryB, LB, sizesB, ncompB);
    }
    gbar(flags, 4);

    // P5: cross-strip merges (bits2, bg)
    if (t < 8) {
        int item = blk * 8 + t;
        if (item < NBOUND) {
            int img = item / 248;
            int r = item - img * 248;
            int gw = img * 4096 + ((r >> 3) + 1) * SROWS * 8 + (r & 7);
            merge_bound_item(bits2, ~0ull, carryB, LB, gw, r & 7);
        }
    }
    gbar(flags, 5);

    // P6: flatten + count (bits2, bg) -> sizesB
    flatten_block(bits2, ~0ull, carryB, LB, sizesB, ncompB, blk, t, U.ha.hk, U.ha.hv);
    gbar(flags, 6);

    // P7: fill_holes(<301) + erode(d2) + opening(d5) + CCL3 strip -> bits3, set A
    {
        int img = blk >> 5, si = blk & 31;
        int gyTop = si * 16 - 12;
        for (int lw = t; lw < 320; lw += 256) {              // load + fill-holes
            int gy = gyTop + (lw >> 3);
            int w = lw & 7;
            uint64_t v = 0;
            if (gy >= 0 && gy < H)
                v = fill_word(bits2, carryB, LB, sizesB, 301, img * 4096 + gy * 8 + w);
            U.mo.A[lw] = v;
        }
        __syncthreads();
        for (int lw = t; lw < 320; lw += 256) {              // erode disk(2)
            int lr = lw >> 3;
            if (lr >= 2 && lr <= 37) U.mo.B[lw] = morph_word_lds<2, true>(U.mo.A, lr, lw & 7, gyTop);
        }
        __syncthreads();
        for (int lw = t; lw < 320; lw += 256) {              // erode disk(5)
            int lr = lw >> 3;
            if (lr >= 7 && lr <= 32) U.mo.A[lw] = morph_word_lds<5, true>(U.mo.B, lr, lw & 7, gyTop);
        }
        __syncthreads();
        for (int lw = t; lw < 320; lw += 256) {              // dilate disk(5)
            int lr = lw >> 3;
            if (lr >= 12 && lr <= 27) U.mo.B[lw] = morph_word_lds<5, false>(U.mo.A, lr, lw & 7, gyTop);
        }
        __syncthreads();
        uint64_t m3 = 0ull;
        if (t < SWORDS) {
            m3 = U.mo.B[t + 96];        // local rows 12..27 = this strip
            bits3[blk * SWORDS + t] = m3;
        }
        // par aliases mo — safe: all mo.B reads (m3) happen before body's first
        // par write, which is behind two __syncthreads
        strip_ccl_body(m3, sw, scarry, U.par, blk, t, carryA, LA, sizesA, ncompA);
    }
    gbar(flags, 7);

    // P8: cross-strip merges (bits3, fg)
    if (t < 8) {
        int item = blk * 8 + t;
        if (item < NBOUND) {
            int img = item / 248;
            int r = item - img * 248;
            int gw = img * 4096 + ((r >> 3) + 1) * SROWS * 8 + (r & 7);
            merge_bound_item(bits3, 0ull, carryA, LA, gw, r & 7);
        }
    }
    gbar(flags, 8);

    // P9: flatten + count (bits3, fg) -> sizesA, ncompA
    flatten_block(bits3, 0ull, carryA, LA, sizesA, ncompA, blk, t, U.ha.hk, U.ha.hv);
    gbar(flags, 9);

    // P10: remove_small_objects(2000,guard) + dilate(d1) + float4 out
    // 1024 8-row segments -> 2 per block
    for (int k = 0; k < 2; ++k) {
        int seg = blk * 2 + k;
        int img = seg >> 6, s8 = seg & 63;
        keep_dilate_seg(bits3, carryA, LA, sizesA, ncompA, out,
                        img, s8 * 8, t, U.kd.kb, U.kd.db);
        __syncthreads();
    }
}

// ---------------------------------------------------------------------------
// Host side — memset(flags) + 1 regular dispatch
// ---------------------------------------------------------------------------
extern "C" void kernel_launch(void* const* d_in, const int* in_sizes, int n_in,
                              void* d_out, int out_size, void* d_ws, size_t ws_size,
                              hipStream_t stream) {
    const float* in = (const float*)d_in[0];
    float* out = (float*)d_out;

    uint8_t* ws = (uint8_t*)d_ws;
    int* LA      = (int*)ws;                                  // 16 MB
    int* sizesA  = (int*)(ws + (size_t)NTOT * 4);             // 16 MB
    int* LB      = (int*)(ws + (size_t)NTOT * 8);             // 16 MB
    int* sizesB  = (int*)(ws + (size_t)NTOT * 12);            // 16 MB
    uint64_t* bits1 = (uint64_t*)(ws + (size_t)NTOT * 16);    // 512 KB
    uint64_t* bits2 = bits1 + NWORDS;                         // 512 KB
    uint64_t* bits3 = bits2 + NWORDS;                         // 512 KB
    int* carryA = (int*)(bits3 + NWORDS);                     // 256 KB
    int* carryB = carryA + NWORDS;                            // 256 KB
    int* ncompA = carryB + NWORDS;                            // 64 B
    int* ncompB = ncompA + BATCH;                             // 64 B
    int* flags  = ncompB + BATCH;                             // 512 flag lines + go

    hipMemsetAsync(flags, 0, (NSTRIPS * FLAG_STRIDE + FLAG_STRIDE) * sizeof(int),
                   stream);

    k_mega<<<NSTRIPS, 256, 0, stream>>>((const float4*)in, out,
                                        LA, sizesA, LB, sizesB,
                                        bits1, bits2, bits3,
                                        carryA, carryB, ncompA, ncompB, flags);
}

// Round 4
// 194.046 us; speedup vs baseline: 3.7157x; 1.6512x over previous
//
#include <hip/hip_runtime.h>
#include <stdint.h>

#define BATCH 16
#define H 512
#define W 512
#define HW (H * W)
#define NTOT (BATCH * HW)
#define NWORDS (NTOT / 64)      // 65536 packed words, 8 per row, 4096 per image

#define SROWS 16                // CCL strip = 16 rows
#define SWORDS 128              // words per CCL strip
#define SPIX 8192               // pixels per CCL strip
#define NSTRIPS (NWORDS / SWORDS)   // 512 strips (never straddle images)
#define NBOUND (BATCH * 248)        // 3968 strip-boundary words

#define FLAG_STRIDE 16              // 64 B per flag line
#define SPIN_LIMIT (1 << 20)        // hang-insurance: give up loudly, not hang

// ---------------------------------------------------------------------------
// Agent-scope relaxed accessors. Round-3 proved on-silicon that relaxed
// agent atomics are individually coherent across XCDs (the barrier flags
// propagated with no covering fence). All cross-block workspace traffic goes
// through these -> NO __threadfence anywhere in the kernel. This kills the
// per-block L2 writeback/invalidate storm that cost ~25 us/barrier in r2/r3.
// ---------------------------------------------------------------------------
__device__ __forceinline__ int ald(const int* p) {
    return __hip_atomic_load((int*)p, __ATOMIC_RELAXED, __HIP_MEMORY_SCOPE_AGENT);
}
__device__ __forceinline__ void ast(int* p, int v) {
    __hip_atomic_store(p, v, __ATOMIC_RELAXED, __HIP_MEMORY_SCOPE_AGENT);
}
__device__ __forceinline__ uint64_t ald64(const uint64_t* p) {
    return __hip_atomic_load((uint64_t*)p, __ATOMIC_RELAXED, __HIP_MEMORY_SCOPE_AGENT);
}
__device__ __forceinline__ void ast64(uint64_t* p, uint64_t v) {
    __hip_atomic_store(p, v, __ATOMIC_RELAXED, __HIP_MEMORY_SCOPE_AGENT);
}

// ---------------------------------------------------------------------------
// Union-find (global): atomicMin keeps parent <= child (monotone) -> acyclic;
// stale reads only cost retries. find_root_c path-compresses. Reads are
// coherence-point loads (ald) so cross-XCD progress is guaranteed.
// ---------------------------------------------------------------------------
__device__ __forceinline__ int find_root_c(int* L, int x) {
    int r = x, p = ald(&L[r]);
    while (p != r) { r = p; p = ald(&L[r]); }
    if (ald(&L[x]) != r) atomicMin(&L[x], r);
    return r;
}

__device__ void merge_uf(int* L, int a, int b) {
    while (true) {
        a = find_root_c(L, a);
        b = find_root_c(L, b);
        if (a == b) return;
        int lo = a < b ? a : b;
        int hi = a < b ? b : a;
        int old = atomicMin(&L[hi], lo);
        if (old == hi) return;
        a = lo; b = old;
    }
}

__device__ __forceinline__ int find_root_lds(int* P, int x) {
    int r = x, p = P[r];
    while (p != r) { r = p; p = P[r]; }
    return r;
}

__device__ void merge_lds(int* P, int a, int b) {
    while (true) {
        a = find_root_lds(P, a);
        b = find_root_lds(P, b);
        if (a == b) return;
        int lo = a < b ? a : b;
        int hi = a < b ? b : a;
        int old = atomicMin(&P[hi], lo);
        if (old == hi) return;
        a = lo; b = old;
    }
}

// start index of the run containing bit i of word m (base = pixel idx of bit0)
__device__ __forceinline__ int start_of(uint64_t m, int i, int cv, int base) {
    uint64_t below = i ? ((~m) & ((1ull << i) - 1)) : 0ull;
    if (below == 0) return (cv >= 0) ? cv : base;
    int hz = 63 - __builtin_clzll(below);
    return base + hz + 1;
}

// remove-small transform of one word (fg comps; pure function of CCL data)
__device__ uint64_t keep_word(const uint64_t* __restrict__ bits,
                              const int* __restrict__ carry, const int* __restrict__ L,
                              const int* __restrict__ sizes, const int* __restrict__ ncomp,
                              int minsz, int gw) {
    uint64_t m = ald64(&bits[gw]);
    uint64_t res = m;
    if (m && ald(&ncomp[gw >> 12]) > 1) {
        int cv = ald(&carry[gw]);
        int base = gw << 6;
        while (m) {
            int s = __builtin_ctzll(m);
            uint64_t rest = m >> s;
            uint64_t nr = ~rest;
            int len = nr ? __builtin_ctzll(nr) : (64 - s);
            uint64_t piece = ((len >= 64) ? ~0ull : ((1ull << len) - 1)) << s;
            int start = (s == 0 && cv >= 0) ? cv : (base + s);
            if (ald(&sizes[ald(&L[start])]) < minsz) res &= ~piece;
            m &= ~piece;
        }
    }
    return res;
}

// fill-holes transform of one word (bg comps; needs inv=1 CCL data)
__device__ uint64_t fill_word(const uint64_t* __restrict__ bits,
                              const int* __restrict__ carry, const int* __restrict__ L,
                              const int* __restrict__ sizes, int minsz, int gw) {
    uint64_t fg = ald64(&bits[gw]);
    uint64_t bg = ~fg;
    uint64_t res = fg;
    int cv = ald(&carry[gw]);
    int base = gw << 6;
    while (bg) {
        int s = __builtin_ctzll(bg);
        uint64_t rest = bg >> s;
        uint64_t nr = ~rest;
        int len = nr ? __builtin_ctzll(nr) : (64 - s);
        uint64_t piece = ((len >= 64) ? ~0ull : ((1ull << len) - 1)) << s;
        int start = (s == 0 && cv >= 0) ? cv : (base + s);
        if (ald(&sizes[ald(&L[start])]) < minsz) res |= piece;
        bg &= ~piece;
    }
    return res;
}

// one morph output word from an LDS window; gyTop = global row of local row 0
template <int R, bool ERODE>
__device__ uint64_t morph_word_lds(const uint64_t* buf, int lrow, int w, int gyTop) {
    const uint64_t BORDER = ERODE ? ~0ull : 0ull;
    uint64_t res = ERODE ? ~0ull : 0ull;
#pragma unroll
    for (int dy = -R; dy <= R; ++dy) {
        int lr = lrow + dy;
        int gy = gyTop + lr;
        if (gy < 0 || gy >= H) continue;       // image border rows = identity
        int v = R * R - dy * dy;
        int kx = 0;
        while ((kx + 1) * (kx + 1) <= v) ++kx;
        uint64_t cur = buf[lr * 8 + w];
        uint64_t prv = (w > 0) ? buf[lr * 8 + w - 1] : BORDER;
        uint64_t nxt = (w < 7) ? buf[lr * 8 + w + 1] : BORDER;
        uint64_t acc = cur;
#pragma unroll
        for (int dx = 1; dx <= kx; ++dx) {
            uint64_t right = (cur >> dx) | (nxt << (64 - dx));
            uint64_t left  = (cur << dx) | (prv >> (64 - dx));
            if (ERODE) acc &= right & left;
            else       acc |= right | left;
        }
        if (ERODE) res &= acc;
        else       res |= acc;
    }
    return res;
}

// ---------------------------------------------------------------------------
// Strip-local CCL body (guarded for blockDim 256: threads with t >= SWORDS
// pass m = 0 and just participate in barriers). Publishes via ast/ast64.
// ---------------------------------------------------------------------------
__device__ void strip_ccl_body(uint64_t m, uint64_t* sw, int* scarry, int* par,
                               int blk, int t,
                               int* __restrict__ carry, int* __restrict__ L,
                               int* __restrict__ sizes, int* __restrict__ ncomp) {
    if (t < SWORDS) sw[t] = m;
    __syncthreads();

    if (t < SROWS) {                    // per-row carries
        int cv = -1;
        for (int i = 0; i < 8; ++i) {
            int lw = t * 8 + i;
            scarry[lw] = cv;
            uint64_t w = sw[lw];
            if (w >> 63) {
                uint64_t z = ~w;
                if (z == 0) { if (cv < 0) cv = lw << 6; }
                else { int hz = 63 - __builtin_clzll(z); cv = (lw << 6) + hz + 1; }
            } else cv = -1;
        }
    }
    __syncthreads();

    int lbase = t << 6;
    int cv = -1;
    uint64_t starts = 0ull;
    if (t < SWORDS) {
        cv = scarry[t];
        ast(&carry[blk * SWORDS + t], (cv >= 0) ? (blk * SPIX + cv) : -1);
        starts = m & ~((m << 1) | ((cv >= 0) ? 1ull : 0ull));
        uint64_t ss = starts;
        while (ss) {
            int s = __builtin_ctzll(ss);
            par[lbase + s] = lbase + s;
            ss &= ss - 1;
        }
    }
    __syncthreads();

    if (t >= 8 && t < SWORDS && m) {    // intra-strip vertical unions
        uint64_t up = sw[t - 8];
        uint64_t cand = m & up;
        if (cand) {
            uint64_t curprev = (t & 7) ? sw[t - 1] : 0ull;
            uint64_t upprev  = (t & 7) ? sw[t - 9] : 0ull;
            uint64_t curl = (m << 1) | (curprev >> 63);
            uint64_t upl  = (up << 1) | (upprev >> 63);
            cand &= ~(curl & upl);
            int cvu = scarry[t - 8];
            while (cand) {
                int i = __builtin_ctzll(cand);
                int sP = start_of(m, i, cv, lbase);
                int sQ = start_of(up, i, cvu, lbase - 512);
                merge_lds(par, sP, sQ);
                cand &= cand - 1;
            }
        }
    }
    __syncthreads();

    if (t < SWORDS) {                   // publish depth-1 trees
        int gpix = blk * SPIX;
        uint64_t ss = starts;
        while (ss) {
            int s = __builtin_ctzll(ss);
            int ls = lbase + s;
            int r = find_root_lds(par, ls);
            ast(&L[gpix + ls], gpix + r);
            if (r == ls) ast(&sizes[gpix + ls], 0);
            ss &= ss - 1;
        }
    }
    if (t == 0 && (blk & 31) == 0) ast(&ncomp[blk >> 5], 0);  // 32 strips/image
}

// one cross-strip boundary word (y % 16 == 0, y != 0)
__device__ void merge_bound_item(const uint64_t* __restrict__ bits, uint64_t inv64,
                                 const int* __restrict__ carry, int* __restrict__ L,
                                 int gw, int w) {
    uint64_t cur = ald64(&bits[gw]) ^ inv64;
    uint64_t up  = ald64(&bits[gw - 8]) ^ inv64;
    uint64_t cand = cur & up;
    if (!cand) return;
    uint64_t curprev = w ? (ald64(&bits[gw - 1]) ^ inv64) : 0ull;
    uint64_t upprev  = w ? (ald64(&bits[gw - 9]) ^ inv64) : 0ull;
    uint64_t curl = (cur << 1) | (curprev >> 63);
    uint64_t upl  = (up << 1)  | (upprev >> 63);
    cand &= ~(curl & upl);
    if (!cand) return;
    int cvc = ald(&carry[gw]), cvu = ald(&carry[gw - 8]);
    int base = gw << 6;
    while (cand) {
        int i = __builtin_ctzll(cand);
        int sP = start_of(cur, i, cvc, base);
        int sQ = start_of(up, i, cvu, base - W);
        merge_uf(L, sP, sQ);
        cand &= cand - 1;
    }
}

// flatten+count for one strip's 128 words (per-block LDS hash)
__device__ void flatten_block(const uint64_t* __restrict__ bits, uint64_t inv64,
                              const int* __restrict__ carry, int* __restrict__ L,
                              int* __restrict__ sizes, int* __restrict__ ncomp,
                              int blk, int t, int* hk, int* hv) {
    if (t < 128) { hk[t] = -1; hv[t] = 0; }
    __syncthreads();
    if (t < SWORDS) {
        int gw = blk * SWORDS + t;
        uint64_t m = ald64(&bits[gw]) ^ inv64;
        if (m) {
            int cv = ald(&carry[gw]);
            int base = gw << 6;
            while (m) {
                int s = __builtin_ctzll(m);
                uint64_t rest = m >> s;
                uint64_t nr = ~rest;
                int len = nr ? __builtin_ctzll(nr) : (64 - s);
                uint64_t piece = ((len >= 64) ? ~0ull : ((1ull << len) - 1)) << s;
                bool initial = !(s == 0 && cv >= 0);
                int start = initial ? (base + s) : cv;
                int r = find_root_c(L, start);
                if (initial && r == start) atomicAdd(&ncomp[gw >> 12], 1);
                int cnt = __popcll(piece);
                uint32_t h = ((uint32_t)r * 2654435761u) >> 25;
                bool done = false;
                for (int tt = 0; tt < 16; ++tt) {
                    int slot = (h + tt) & 127;
                    int k = hk[slot];
                    if (k == -1) k = atomicCAS(&hk[slot], -1, r);
                    if (k == -1 || k == r) { atomicAdd(&hv[slot], cnt); done = true; break; }
                }
                if (!done) atomicAdd(&sizes[r], cnt);
                m &= ~piece;
            }
        }
    }
    __syncthreads();
    if (t < 128 && hk[t] != -1) atomicAdd(&sizes[hk[t]], hv[t]);
}

// keep + dilate(disk1) + float4 cast for one 8-row segment (256 threads)
__device__ void keep_dilate_seg(const uint64_t* __restrict__ bits,
                                const int* __restrict__ carry, const int* __restrict__ L,
                                const int* __restrict__ sizes, const int* __restrict__ ncomp,
                                float* __restrict__ out,
                                int img, int y0, int t, uint64_t* kb, uint64_t* db) {
    if (t < 80) {
        int lr = t >> 3;
        int w = t & 7;
        int gy = y0 - 1 + lr;
        uint64_t v = 0;
        if (gy >= 0 && gy < H)
            v = keep_word(bits, carry, L, sizes, ncomp, 2000, img * 4096 + gy * 8 + w);
        kb[t] = v;
    }
    __syncthreads();
    if (t < 64) {
        int r = t >> 3, w = t & 7;
        uint64_t cur = kb[(r + 1) * 8 + w];
        uint64_t up  = kb[r * 8 + w];
        uint64_t dn  = kb[(r + 2) * 8 + w];
        uint64_t prv = w ? kb[(r + 1) * 8 + w - 1] : 0ull;
        uint64_t nxt = (w < 7) ? kb[(r + 1) * 8 + w + 1] : 0ull;
        db[t] = cur | up | dn | (cur << 1) | (prv >> 63) | (cur >> 1) | (nxt << 63);
    }
    __syncthreads();

    int q0 = t * 16;                    // 16 consecutive pixels per thread
    uint64_t wd = db[q0 >> 6];
    int sh = q0 & 63;
    float4* o = (float4*)(out + (size_t)img * HW + (size_t)y0 * W + q0);
#pragma unroll
    for (int k = 0; k < 4; ++k) {
        uint32_t nib = (uint32_t)(wd >> (sh + k * 4)) & 0xFu;
        float4 f;
        f.x = (nib & 1u) ? 1.0f : 0.0f;
        f.y = (nib & 2u) ? 1.0f : 0.0f;
        f.z = (nib & 4u) ? 1.0f : 0.0f;
        f.w = (nib & 8u) ? 1.0f : 0.0f;
        o[k] = f;
    }
}

// ---------------------------------------------------------------------------
// FENCE-FREE grid barrier. All shared data moves through agent-scope (sc1)
// accesses, so the only release obligation is "my outstanding stores/RMWs
// have reached the coherence point" = s_waitcnt vmcnt(0). No acquire needed:
// every post-barrier read is itself coherence-point-fresh. Arrival is the
// (proven) contention-free flag scheme: block i store-releases flag[i];
// block 0's 256 threads poll all 512 flags; one `go` word releases everyone.
// ---------------------------------------------------------------------------
__device__ __forceinline__ void gbar(int* flags, int phase) {
    int* go = flags + NSTRIPS * FLAG_STRIDE;
    __syncthreads();
    if (threadIdx.x == 0) {
        asm volatile("s_waitcnt vmcnt(0)" ::: "memory");   // release: stores ack'd
        ast(&flags[blockIdx.x * FLAG_STRIDE], phase);
    }
    if (blockIdx.x == 0) {
        int spins = 0;
        while (ald(&flags[threadIdx.x * FLAG_STRIDE]) < phase && ++spins < SPIN_LIMIT)
            __builtin_amdgcn_s_sleep(1);
        while (ald(&flags[(threadIdx.x + 256) * FLAG_STRIDE]) < phase && ++spins < SPIN_LIMIT)
            __builtin_amdgcn_s_sleep(1);
        __syncthreads();
        if (threadIdx.x == 0) ast(go, phase);
    }
    if (threadIdx.x == 0) {
        int spins = 0;
        while (ald(go) < phase && ++spins < SPIN_LIMIT)
            __builtin_amdgcn_s_sleep(1);
    }
    __syncthreads();
}

// ---------------------------------------------------------------------------
// MEGA: whole pipeline, ONE regular kernel, 9 fence-free barriers.
// 512 blocks x 256 thr, 34.3 KB LDS, __launch_bounds__(256,2) -> all blocks
// co-resident (2/CU); plain launch (r3 proved spin-barriers work this way).
// ---------------------------------------------------------------------------
__global__ __launch_bounds__(256, 2) void k_mega(
        const float4* __restrict__ in4, float* __restrict__ out,
        int* LA, int* sizesA, int* LB, int* sizesB,
        uint64_t* bits1, uint64_t* bits2, uint64_t* bits3,
        int* carryA, int* carryB, int* ncompA, int* ncompB, int* flags) {
    __shared__ uint64_t sw[SWORDS];
    __shared__ int scarry[SWORDS];
    __shared__ union US {
        int par[SPIX];                                     // 32 KB (CCL)
        struct { uint64_t A[320]; uint64_t B[320]; } mo;   // 5 KB (morph)
        struct { int hk[128]; int hv[128]; } ha;           // 1 KB (flatten hash)
        struct { uint64_t kb[80]; uint64_t db[64]; } kd;   // 1.1 KB (out stage)
    } U;
    int blk = blockIdx.x;
    int t = threadIdx.x;

    // P0: threshold + pack, STRIP-LOCAL (block packs its own 128 words)
#pragma unroll
    for (int it = 0; it < 8; ++it) {
        int q = blk * (SPIX / 4) + it * 256 + t;           // quad index
        float4 v = in4[q];
        uint32_t nib = (v.x > 0.0f ? 1u : 0u) | (v.y > 0.0f ? 2u : 0u) |
                       (v.z > 0.0f ? 4u : 0u) | (v.w > 0.0f ? 8u : 0u);
        uint64_t val = (uint64_t)nib << (4 * (t & 15));
        val |= __shfl_xor(val, 1);
        val |= __shfl_xor(val, 2);
        val |= __shfl_xor(val, 4);
        val |= __shfl_xor(val, 8);
        if ((t & 15) == 0) ast64(&bits1[q >> 4], val);
    }
    __syncthreads();

    // P1: CCL1 strip phase (fg of bits1) -> set A
    {
        uint64_t m = (t < SWORDS) ? ald64(&bits1[blk * SWORDS + t]) : 0ull;
        strip_ccl_body(m, sw, scarry, U.par, blk, t, carryA, LA, sizesA, ncompA);
    }
    gbar(flags, 1);

    // P2: cross-strip merges (bits1, fg) — 3968 items spread over all blocks
    if (t < 8) {
        int item = blk * 8 + t;
        if (item < NBOUND) {
            int img = item / 248;
            int r = item - img * 248;
            int gw = img * 4096 + ((r >> 3) + 1) * SROWS * 8 + (r & 7);
            merge_bound_item(bits1, 0ull, carryA, LA, gw, r & 7);
        }
    }
    gbar(flags, 2);

    // P3: flatten + count (bits1, fg) -> sizesA, ncompA
    flatten_block(bits1, 0ull, carryA, LA, sizesA, ncompA, blk, t, U.ha.hk, U.ha.hv);
    gbar(flags, 3);

    // P4: remove_small_objects(2000,guard) -> bits2, fused with CCL2 strip (bg)
    {
        uint64_t m = 0ull;
        if (t < SWORDS) {
            int gw = blk * SWORDS + t;
            uint64_t kw = keep_word(bits1, carryA, LA, sizesA, ncompA, 2000, gw);
            ast64(&bits2[gw], kw);
            m = ~kw;
        }
        strip_ccl_body(m, sw, scarry, U.par, blk, t, carryB, LB, sizesB, ncompB);
    }
    gbar(flags, 4);

    // P5: cross-strip merges (bits2, bg)
    if (t < 8) {
        int item = blk * 8 + t;
        if (item < NBOUND) {
            int img = item / 248;
            int r = item - img * 248;
            int gw = img * 4096 + ((r >> 3) + 1) * SROWS * 8 + (r & 7);
            merge_bound_item(bits2, ~0ull, carryB, LB, gw, r & 7);
        }
    }
    gbar(flags, 5);

    // P6: flatten + count (bits2, bg) -> sizesB
    flatten_block(bits2, ~0ull, carryB, LB, sizesB, ncompB, blk, t, U.ha.hk, U.ha.hv);
    gbar(flags, 6);

    // P7: fill_holes(<301) + erode(d2) + opening(d5) + CCL3 strip -> bits3, set A
    {
        int img = blk >> 5, si = blk & 31;
        int gyTop = si * 16 - 12;
        for (int lw = t; lw < 320; lw += 256) {              // load + fill-holes
            int gy = gyTop + (lw >> 3);
            int w = lw & 7;
            uint64_t v = 0;
            if (gy >= 0 && gy < H)
                v = fill_word(bits2, carryB, LB, sizesB, 301, img * 4096 + gy * 8 + w);
            U.mo.A[lw] = v;
        }
        __syncthreads();
        for (int lw = t; lw < 320; lw += 256) {              // erode disk(2)
            int lr = lw >> 3;
            if (lr >= 2 && lr <= 37) U.mo.B[lw] = morph_word_lds<2, true>(U.mo.A, lr, lw & 7, gyTop);
        }
        __syncthreads();
        for (int lw = t; lw < 320; lw += 256) {              // erode disk(5)
            int lr = lw >> 3;
            if (lr >= 7 && lr <= 32) U.mo.A[lw] = morph_word_lds<5, true>(U.mo.B, lr, lw & 7, gyTop);
        }
        __syncthreads();
        for (int lw = t; lw < 320; lw += 256) {              // dilate disk(5)
            int lr = lw >> 3;
            if (lr >= 12 && lr <= 27) U.mo.B[lw] = morph_word_lds<5, false>(U.mo.A, lr, lw & 7, gyTop);
        }
        __syncthreads();
        uint64_t m3 = 0ull;
        if (t < SWORDS) {
            m3 = U.mo.B[t + 96];        // local rows 12..27 = this strip
            ast64(&bits3[blk * SWORDS + t], m3);
        }
        // par aliases mo — safe: all mo.B reads (m3) happen before body's first
        // par write, which is behind two __syncthreads
        strip_ccl_body(m3, sw, scarry, U.par, blk, t, carryA, LA, sizesA, ncompA);
    }
    gbar(flags, 7);

    // P8: cross-strip merges (bits3, fg)
    if (t < 8) {
        int item = blk * 8 + t;
        if (item < NBOUND) {
            int img = item / 248;
            int r = item - img * 248;
            int gw = img * 4096 + ((r >> 3) + 1) * SROWS * 8 + (r & 7);
            merge_bound_item(bits3, 0ull, carryA, LA, gw, r & 7);
        }
    }
    gbar(flags, 8);

    // P9: flatten + count (bits3, fg) -> sizesA, ncompA
    flatten_block(bits3, 0ull, carryA, LA, sizesA, ncompA, blk, t, U.ha.hk, U.ha.hv);
    gbar(flags, 9);

    // P10: remove_small_objects(2000,guard) + dilate(d1) + float4 out
    // 1024 8-row segments -> 2 per block
    for (int k = 0; k < 2; ++k) {
        int seg = blk * 2 + k;
        int img = seg >> 6, s8 = seg & 63;
        keep_dilate_seg(bits3, carryA, LA, sizesA, ncompA, out,
                        img, s8 * 8, t, U.kd.kb, U.kd.db);
        __syncthreads();
    }
}

// ---------------------------------------------------------------------------
// Host side — memset(flags) + 1 regular dispatch
// ---------------------------------------------------------------------------
extern "C" void kernel_launch(void* const* d_in, const int* in_sizes, int n_in,
                              void* d_out, int out_size, void* d_ws, size_t ws_size,
                              hipStream_t stream) {
    const float* in = (const float*)d_in[0];
    float* out = (float*)d_out;

    uint8_t* ws = (uint8_t*)d_ws;
    int* LA      = (int*)ws;                                  // 16 MB
    int* sizesA  = (int*)(ws + (size_t)NTOT * 4);             // 16 MB
    int* LB      = (int*)(ws + (size_t)NTOT * 8);             // 16 MB
    int* sizesB  = (int*)(ws + (size_t)NTOT * 12);            // 16 MB
    uint64_t* bits1 = (uint64_t*)(ws + (size_t)NTOT * 16);    // 512 KB
    uint64_t* bits2 = bits1 + NWORDS;                         // 512 KB
    uint64_t* bits3 = bits2 + NWORDS;                         // 512 KB
    int* carryA = (int*)(bits3 + NWORDS);                     // 256 KB
    int* carryB = carryA + NWORDS;                            // 256 KB
    int* ncompA = carryB + NWORDS;                            // 64 B
    int* ncompB = ncompA + BATCH;                             // 64 B
    int* flags  = ncompB + BATCH;                             // 512 flag lines + go

    hipMemsetAsync(flags, 0, (NSTRIPS * FLAG_STRIDE + FLAG_STRIDE) * sizeof(int),
                   stream);

    k_mega<<<NSTRIPS, 256, 0, stream>>>((const float4*)in, out,
                                        LA, sizesA, LB, sizesB,
                                        bits1, bits2, bits3,
                                        carryA, carryB, ncompA, ncompB, flags);
}

// Round 5
// 192.935 us; speedup vs baseline: 3.7371x; 1.0058x over previous
//
#include <hip/hip_runtime.h>
#include <stdint.h>

#define BATCH 16
#define H 512
#define W 512
#define HW (H * W)
#define NTOT (BATCH * HW)
#define NWORDS (NTOT / 64)      // 65536 packed words, 8 per row, 4096 per image

#define SROWS 16                // CCL strip = 16 rows
#define SWORDS 128              // words per CCL strip
#define SPIX 8192               // pixels per CCL strip
#define NSTRIPS (NWORDS / SWORDS)   // 512 strips (never straddle images)
#define IMG_STRIPS 32               // strips per image
#define NBOUND_IMG 248              // boundary words per image (31 rows x 8)

#define SPIN_LIMIT (1 << 20)        // hang-insurance: give up loudly, not hang

// ---------------------------------------------------------------------------
// Agent-scope relaxed accessors (sc1, coherence-point). Proven r3/r4: relaxed
// agent atomics are individually coherent across XCDs with NO fences. All
// cross-block workspace traffic goes through these; zero __threadfence in the
// kernel (r4: fence removal cut 269->135 us).
// ---------------------------------------------------------------------------
__device__ __forceinline__ int ald(const int* p) {
    return __hip_atomic_load((int*)p, __ATOMIC_RELAXED, __HIP_MEMORY_SCOPE_AGENT);
}
__device__ __forceinline__ void ast(int* p, int v) {
    __hip_atomic_store(p, v, __ATOMIC_RELAXED, __HIP_MEMORY_SCOPE_AGENT);
}
__device__ __forceinline__ uint64_t ald64(const uint64_t* p) {
    return __hip_atomic_load((uint64_t*)p, __ATOMIC_RELAXED, __HIP_MEMORY_SCOPE_AGENT);
}
__device__ __forceinline__ void ast64(uint64_t* p, uint64_t v) {
    __hip_atomic_store(p, v, __ATOMIC_RELAXED, __HIP_MEMORY_SCOPE_AGENT);
}

// ---------------------------------------------------------------------------
// Union-find (global): atomicMin keeps parent <= child (monotone) -> acyclic;
// stale reads only cost retries. find_root_c path-compresses.
// ---------------------------------------------------------------------------
__device__ __forceinline__ int find_root_c(int* L, int x) {
    int r = x, p = ald(&L[r]);
    while (p != r) { r = p; p = ald(&L[r]); }
    if (ald(&L[x]) != r) atomicMin(&L[x], r);
    return r;
}

__device__ void merge_uf(int* L, int a, int b) {
    while (true) {
        a = find_root_c(L, a);
        b = find_root_c(L, b);
        if (a == b) return;
        int lo = a < b ? a : b;
        int hi = a < b ? b : a;
        int old = atomicMin(&L[hi], lo);
        if (old == hi) return;
        a = lo; b = old;
    }
}

__device__ __forceinline__ int find_root_lds(int* P, int x) {
    int r = x, p = P[r];
    while (p != r) { r = p; p = P[r]; }
    return r;
}

__device__ void merge_lds(int* P, int a, int b) {
    while (true) {
        a = find_root_lds(P, a);
        b = find_root_lds(P, b);
        if (a == b) return;
        int lo = a < b ? a : b;
        int hi = a < b ? b : a;
        int old = atomicMin(&P[hi], lo);
        if (old == hi) return;
        a = lo; b = old;
    }
}

// start index of the run containing bit i of word m (base = pixel idx of bit0)
__device__ __forceinline__ int start_of(uint64_t m, int i, int cv, int base) {
    uint64_t below = i ? ((~m) & ((1ull << i) - 1)) : 0ull;
    if (below == 0) return (cv >= 0) ? cv : base;
    int hz = 63 - __builtin_clzll(below);
    return base + hz + 1;
}

// remove-small transform of one word (fg comps; pure function of CCL data)
__device__ uint64_t keep_word(const uint64_t* __restrict__ bits,
                              const int* __restrict__ carry, const int* __restrict__ L,
                              const int* __restrict__ sizes, const int* __restrict__ ncomp,
                              int minsz, int gw) {
    uint64_t m = ald64(&bits[gw]);
    uint64_t res = m;
    if (m && ald(&ncomp[gw >> 12]) > 1) {
        int cv = ald(&carry[gw]);
        int base = gw << 6;
        while (m) {
            int s = __builtin_ctzll(m);
            uint64_t rest = m >> s;
            uint64_t nr = ~rest;
            int len = nr ? __builtin_ctzll(nr) : (64 - s);
            uint64_t piece = ((len >= 64) ? ~0ull : ((1ull << len) - 1)) << s;
            int start = (s == 0 && cv >= 0) ? cv : (base + s);
            if (ald(&sizes[ald(&L[start])]) < minsz) res &= ~piece;
            m &= ~piece;
        }
    }
    return res;
}

// fill-holes transform of one word (bg comps; needs inv=1 CCL data)
__device__ uint64_t fill_word(const uint64_t* __restrict__ bits,
                              const int* __restrict__ carry, const int* __restrict__ L,
                              const int* __restrict__ sizes, int minsz, int gw) {
    uint64_t fg = ald64(&bits[gw]);
    uint64_t bg = ~fg;
    uint64_t res = fg;
    int cv = ald(&carry[gw]);
    int base = gw << 6;
    while (bg) {
        int s = __builtin_ctzll(bg);
        uint64_t rest = bg >> s;
        uint64_t nr = ~rest;
        int len = nr ? __builtin_ctzll(nr) : (64 - s);
        uint64_t piece = ((len >= 64) ? ~0ull : ((1ull << len) - 1)) << s;
        int start = (s == 0 && cv >= 0) ? cv : (base + s);
        if (ald(&sizes[ald(&L[start])]) < minsz) res |= piece;
        bg &= ~piece;
    }
    return res;
}

// one morph output word from an LDS window; gyTop = global row of local row 0
template <int R, bool ERODE>
__device__ uint64_t morph_word_lds(const uint64_t* buf, int lrow, int w, int gyTop) {
    const uint64_t BORDER = ERODE ? ~0ull : 0ull;
    uint64_t res = ERODE ? ~0ull : 0ull;
#pragma unroll
    for (int dy = -R; dy <= R; ++dy) {
        int lr = lrow + dy;
        int gy = gyTop + lr;
        if (gy < 0 || gy >= H) continue;       // image border rows = identity
        int v = R * R - dy * dy;
        int kx = 0;
        while ((kx + 1) * (kx + 1) <= v) ++kx;
        uint64_t cur = buf[lr * 8 + w];
        uint64_t prv = (w > 0) ? buf[lr * 8 + w - 1] : BORDER;
        uint64_t nxt = (w < 7) ? buf[lr * 8 + w + 1] : BORDER;
        uint64_t acc = cur;
#pragma unroll
        for (int dx = 1; dx <= kx; ++dx) {
            uint64_t right = (cur >> dx) | (nxt << (64 - dx));
            uint64_t left  = (cur << dx) | (prv >> (64 - dx));
            if (ERODE) acc &= right & left;
            else       acc |= right | left;
        }
        if (ERODE) res &= acc;
        else       res |= acc;
    }
    return res;
}

// ---------------------------------------------------------------------------
// Strip-local CCL body (guarded for blockDim 256: threads with t >= SWORDS
// pass m = 0 and just participate in barriers). Publishes via ast/ast64.
// ---------------------------------------------------------------------------
__device__ void strip_ccl_body(uint64_t m, uint64_t* sw, int* scarry, int* par,
                               int blk, int t,
                               int* __restrict__ carry, int* __restrict__ L,
                               int* __restrict__ sizes, int* __restrict__ ncomp) {
    if (t < SWORDS) sw[t] = m;
    __syncthreads();

    if (t < SROWS) {                    // per-row carries
        int cv = -1;
        for (int i = 0; i < 8; ++i) {
            int lw = t * 8 + i;
            scarry[lw] = cv;
            uint64_t w = sw[lw];
            if (w >> 63) {
                uint64_t z = ~w;
                if (z == 0) { if (cv < 0) cv = lw << 6; }
                else { int hz = 63 - __builtin_clzll(z); cv = (lw << 6) + hz + 1; }
            } else cv = -1;
        }
    }
    __syncthreads();

    int lbase = t << 6;
    int cv = -1;
    uint64_t starts = 0ull;
    if (t < SWORDS) {
        cv = scarry[t];
        ast(&carry[blk * SWORDS + t], (cv >= 0) ? (blk * SPIX + cv) : -1);
        starts = m & ~((m << 1) | ((cv >= 0) ? 1ull : 0ull));
        uint64_t ss = starts;
        while (ss) {
            int s = __builtin_ctzll(ss);
            par[lbase + s] = lbase + s;
            ss &= ss - 1;
        }
    }
    __syncthreads();

    if (t >= 8 && t < SWORDS && m) {    // intra-strip vertical unions
        uint64_t up = sw[t - 8];
        uint64_t cand = m & up;
        if (cand) {
            uint64_t curprev = (t & 7) ? sw[t - 1] : 0ull;
            uint64_t upprev  = (t & 7) ? sw[t - 9] : 0ull;
            uint64_t curl = (m << 1) | (curprev >> 63);
            uint64_t upl  = (up << 1) | (upprev >> 63);
            cand &= ~(curl & upl);
            int cvu = scarry[t - 8];
            while (cand) {
                int i = __builtin_ctzll(cand);
                int sP = start_of(m, i, cv, lbase);
                int sQ = start_of(up, i, cvu, lbase - 512);
                merge_lds(par, sP, sQ);
                cand &= cand - 1;
            }
        }
    }
    __syncthreads();

    if (t < SWORDS) {                   // publish depth-1 trees
        int gpix = blk * SPIX;
        uint64_t ss = starts;
        while (ss) {
            int s = __builtin_ctzll(ss);
            int ls = lbase + s;
            int r = find_root_lds(par, ls);
            ast(&L[gpix + ls], gpix + r);
            if (r == ls) ast(&sizes[gpix + ls], 0);
            ss &= ss - 1;
        }
    }
    if (t == 0 && (blk & 31) == 0) ast(&ncomp[blk >> 5], 0);  // 32 strips/image
}

// one cross-strip boundary word (y % 16 == 0, y != 0)
__device__ void merge_bound_item(const uint64_t* __restrict__ bits, uint64_t inv64,
                                 const int* __restrict__ carry, int* __restrict__ L,
                                 int gw, int w) {
    uint64_t cur = ald64(&bits[gw]) ^ inv64;
    uint64_t up  = ald64(&bits[gw - 8]) ^ inv64;
    uint64_t cand = cur & up;
    if (!cand) return;
    uint64_t curprev = w ? (ald64(&bits[gw - 1]) ^ inv64) : 0ull;
    uint64_t upprev  = w ? (ald64(&bits[gw - 9]) ^ inv64) : 0ull;
    uint64_t curl = (cur << 1) | (curprev >> 63);
    uint64_t upl  = (up << 1)  | (upprev >> 63);
    cand &= ~(curl & upl);
    if (!cand) return;
    int cvc = ald(&carry[gw]), cvu = ald(&carry[gw - 8]);
    int base = gw << 6;
    while (cand) {
        int i = __builtin_ctzll(cand);
        int sP = start_of(cur, i, cvc, base);
        int sQ = start_of(up, i, cvu, base - W);
        merge_uf(L, sP, sQ);
        cand &= cand - 1;
    }
}

// flatten+count for one strip's 128 words (per-block LDS hash)
__device__ void flatten_block(const uint64_t* __restrict__ bits, uint64_t inv64,
                              const int* __restrict__ carry, int* __restrict__ L,
                              int* __restrict__ sizes, int* __restrict__ ncomp,
                              int blk, int t, int* hk, int* hv) {
    if (t < 128) { hk[t] = -1; hv[t] = 0; }
    __syncthreads();
    if (t < SWORDS) {
        int gw = blk * SWORDS + t;
        uint64_t m = ald64(&bits[gw]) ^ inv64;
        if (m) {
            int cv = ald(&carry[gw]);
            int base = gw << 6;
            while (m) {
                int s = __builtin_ctzll(m);
                uint64_t rest = m >> s;
                uint64_t nr = ~rest;
                int len = nr ? __builtin_ctzll(nr) : (64 - s);
                uint64_t piece = ((len >= 64) ? ~0ull : ((1ull << len) - 1)) << s;
                bool initial = !(s == 0 && cv >= 0);
                int start = initial ? (base + s) : cv;
                int r = find_root_c(L, start);
                if (initial && r == start) atomicAdd(&ncomp[gw >> 12], 1);
                int cnt = __popcll(piece);
                uint32_t h = ((uint32_t)r * 2654435761u) >> 25;
                bool done = false;
                for (int tt = 0; tt < 16; ++tt) {
                    int slot = (h + tt) & 127;
                    int k = hk[slot];
                    if (k == -1) k = atomicCAS(&hk[slot], -1, r);
                    if (k == -1 || k == r) { atomicAdd(&hv[slot], cnt); done = true; break; }
                }
                if (!done) atomicAdd(&sizes[r], cnt);
                m &= ~piece;
            }
        }
    }
    __syncthreads();
    if (t < 128 && hk[t] != -1) atomicAdd(&sizes[hk[t]], hv[t]);
}

// keep + dilate(disk1) + float4 cast for one 8-row segment (256 threads)
__device__ void keep_dilate_seg(const uint64_t* __restrict__ bits,
                                const int* __restrict__ carry, const int* __restrict__ L,
                                const int* __restrict__ sizes, const int* __restrict__ ncomp,
                                float* __restrict__ out,
                                int img, int y0, int t, uint64_t* kb, uint64_t* db) {
    if (t < 80) {
        int lr = t >> 3;
        int w = t & 7;
        int gy = y0 - 1 + lr;
        uint64_t v = 0;
        if (gy >= 0 && gy < H)
            v = keep_word(bits, carry, L, sizes, ncomp, 2000, img * 4096 + gy * 8 + w);
        kb[t] = v;
    }
    __syncthreads();
    if (t < 64) {
        int r = t >> 3, w = t & 7;
        uint64_t cur = kb[(r + 1) * 8 + w];
        uint64_t up  = kb[r * 8 + w];
        uint64_t dn  = kb[(r + 2) * 8 + w];
        uint64_t prv = w ? kb[(r + 1) * 8 + w - 1] : 0ull;
        uint64_t nxt = (w < 7) ? kb[(r + 1) * 8 + w + 1] : 0ull;
        db[t] = cur | up | dn | (cur << 1) | (prv >> 63) | (cur >> 1) | (nxt << 63);
    }
    __syncthreads();

    int q0 = t * 16;                    // 16 consecutive pixels per thread
    uint64_t wd = db[q0 >> 6];
    int sh = q0 & 63;
    float4* o = (float4*)(out + (size_t)img * HW + (size_t)y0 * W + q0);
#pragma unroll
    for (int k = 0; k < 4; ++k) {
        uint32_t nib = (uint32_t)(wd >> (sh + k * 4)) & 0xFu;
        float4 f;
        f.x = (nib & 1u) ? 1.0f : 0.0f;
        f.y = (nib & 2u) ? 1.0f : 0.0f;
        f.z = (nib & 4u) ? 1.0f : 0.0f;
        f.w = (nib & 8u) ? 1.0f : 0.0f;
        o[k] = f;
    }
}

// ---------------------------------------------------------------------------
// PER-IMAGE fence-free barrier (r5): components never cross images, so every
// phase is image-local -> sync only the 32 blocks of one image. All-poll-all:
// store own flag (after vmcnt(0) release), 32 threads poll the image's 32
// flags, done. One IF round-trip; no global straggler coupling — the 16
// image-pipelines run fully decoupled.
// Flag layout: image i owns ints [i*32 .. i*32+31] (128 B, own cachelines).
// ---------------------------------------------------------------------------
__device__ __forceinline__ void ibar(int* flags, int img, int si, int phase) {
    int* base = flags + img * 32;
    __syncthreads();
    if (threadIdx.x == 0) {
        asm volatile("s_waitcnt vmcnt(0)" ::: "memory");   // release: stores ack'd
        ast(&base[si], phase);
    }
    if (threadIdx.x < 32) {
        int spins = 0;
        while (ald(&base[threadIdx.x]) < phase && ++spins < SPIN_LIMIT)
            __builtin_amdgcn_s_sleep(1);
    }
    __syncthreads();
}

// ---------------------------------------------------------------------------
// MEGA: whole pipeline, ONE regular kernel, 9 per-image barriers.
// 512 blocks x 256 thr, 34.3 KB LDS, __launch_bounds__(256,2) -> all blocks
// co-resident (2/CU); plain launch (proven r3/r4).
// ---------------------------------------------------------------------------
__global__ __launch_bounds__(256, 2) void k_mega(
        const float4* __restrict__ in4, float* __restrict__ out,
        int* LA, int* sizesA, int* LB, int* sizesB,
        uint64_t* bits1, uint64_t* bits2, uint64_t* bits3,
        int* carryA, int* carryB, int* ncompA, int* ncompB, int* flags) {
    __shared__ uint64_t sw[SWORDS];
    __shared__ int scarry[SWORDS];
    __shared__ union US {
        int par[SPIX];                                     // 32 KB (CCL)
        struct { uint64_t A[320]; uint64_t B[320]; } mo;   // 5 KB (morph)
        struct { int hk[128]; int hv[128]; } ha;           // 1 KB (flatten hash)
        struct { uint64_t kb[80]; uint64_t db[64]; } kd;   // 1.1 KB (out stage)
    } U;
    int blk = blockIdx.x;
    int t = threadIdx.x;
    int img = blk >> 5, si = blk & 31;   // image id, strip-in-image

    // P0: threshold + pack, STRIP-LOCAL (block packs its own 128 words)
#pragma unroll
    for (int it = 0; it < 8; ++it) {
        int q = blk * (SPIX / 4) + it * 256 + t;           // quad index
        float4 v = in4[q];
        uint32_t nib = (v.x > 0.0f ? 1u : 0u) | (v.y > 0.0f ? 2u : 0u) |
                       (v.z > 0.0f ? 4u : 0u) | (v.w > 0.0f ? 8u : 0u);
        uint64_t val = (uint64_t)nib << (4 * (t & 15));
        val |= __shfl_xor(val, 1);
        val |= __shfl_xor(val, 2);
        val |= __shfl_xor(val, 4);
        val |= __shfl_xor(val, 8);
        if ((t & 15) == 0) ast64(&bits1[q >> 4], val);
    }
    __syncthreads();

    // P1: CCL1 strip phase (fg of bits1) -> set A
    {
        uint64_t m = (t < SWORDS) ? ald64(&bits1[blk * SWORDS + t]) : 0ull;
        strip_ccl_body(m, sw, scarry, U.par, blk, t, carryA, LA, sizesA, ncompA);
    }
    ibar(flags, img, si, 1);

    // P2: cross-strip merges (bits1, fg) — image-local: 248 items / 32 blocks
    if (t < 8) {
        int item = si * 8 + t;
        if (item < NBOUND_IMG) {
            int gw = img * 4096 + ((item >> 3) + 1) * SROWS * 8 + (item & 7);
            merge_bound_item(bits1, 0ull, carryA, LA, gw, item & 7);
        }
    }
    ibar(flags, img, si, 2);

    // P3: flatten + count (bits1, fg) -> sizesA, ncompA
    flatten_block(bits1, 0ull, carryA, LA, sizesA, ncompA, blk, t, U.ha.hk, U.ha.hv);
    ibar(flags, img, si, 3);

    // P4: remove_small_objects(2000,guard) -> bits2, fused with CCL2 strip (bg)
    {
        uint64_t m = 0ull;
        if (t < SWORDS) {
            int gw = blk * SWORDS + t;
            uint64_t kw = keep_word(bits1, carryA, LA, sizesA, ncompA, 2000, gw);
            ast64(&bits2[gw], kw);
            m = ~kw;
        }
        strip_ccl_body(m, sw, scarry, U.par, blk, t, carryB, LB, sizesB, ncompB);
    }
    ibar(flags, img, si, 4);

    // P5: cross-strip merges (bits2, bg)
    if (t < 8) {
        int item = si * 8 + t;
        if (item < NBOUND_IMG) {
            int gw = img * 4096 + ((item >> 3) + 1) * SROWS * 8 + (item & 7);
            merge_bound_item(bits2, ~0ull, carryB, LB, gw, item & 7);
        }
    }
    ibar(flags, img, si, 5);

    // P6: flatten + count (bits2, bg) -> sizesB
    flatten_block(bits2, ~0ull, carryB, LB, sizesB, ncompB, blk, t, U.ha.hk, U.ha.hv);
    ibar(flags, img, si, 6);

    // P7: fill_holes(<301) + erode(d2) + opening(d5) + CCL3 strip -> bits3, set A
    {
        int gyTop = si * 16 - 12;
        for (int lw = t; lw < 320; lw += 256) {              // load + fill-holes
            int gy = gyTop + (lw >> 3);
            int w = lw & 7;
            uint64_t v = 0;
            if (gy >= 0 && gy < H)
                v = fill_word(bits2, carryB, LB, sizesB, 301, img * 4096 + gy * 8 + w);
            U.mo.A[lw] = v;
        }
        __syncthreads();
        for (int lw = t; lw < 320; lw += 256) {              // erode disk(2)
            int lr = lw >> 3;
            if (lr >= 2 && lr <= 37) U.mo.B[lw] = morph_word_lds<2, true>(U.mo.A, lr, lw & 7, gyTop);
        }
        __syncthreads();
        for (int lw = t; lw < 320; lw += 256) {              // erode disk(5)
            int lr = lw >> 3;
            if (lr >= 7 && lr <= 32) U.mo.A[lw] = morph_word_lds<5, true>(U.mo.B, lr, lw & 7, gyTop);
        }
        __syncthreads();
        for (int lw = t; lw < 320; lw += 256) {              // dilate disk(5)
            int lr = lw >> 3;
            if (lr >= 12 && lr <= 27) U.mo.B[lw] = morph_word_lds<5, false>(U.mo.A, lr, lw & 7, gyTop);
        }
        __syncthreads();
        uint64_t m3 = 0ull;
        if (t < SWORDS) {
            m3 = U.mo.B[t + 96];        // local rows 12..27 = this strip
            ast64(&bits3[blk * SWORDS + t], m3);
        }
        // par aliases mo — safe: all mo.B reads (m3) happen before body's first
        // par write, which is behind two __syncthreads
        strip_ccl_body(m3, sw, scarry, U.par, blk, t, carryA, LA, sizesA, ncompA);
    }
    ibar(flags, img, si, 7);

    // P8: cross-strip merges (bits3, fg)
    if (t < 8) {
        int item = si * 8 + t;
        if (item < NBOUND_IMG) {
            int gw = img * 4096 + ((item >> 3) + 1) * SROWS * 8 + (item & 7);
            merge_bound_item(bits3, 0ull, carryA, LA, gw, item & 7);
        }
    }
    ibar(flags, img, si, 8);

    // P9: flatten + count (bits3, fg) -> sizesA, ncompA
    flatten_block(bits3, 0ull, carryA, LA, sizesA, ncompA, blk, t, U.ha.hk, U.ha.hv);
    ibar(flags, img, si, 9);

    // P10: remove_small_objects(2000,guard) + dilate(d1) + float4 out
    // 64 8-row segments per image -> 2 per block (image-local)
    for (int k = 0; k < 2; ++k) {
        int seg = blk * 2 + k;          // seg>>6 == img by construction
        int s8 = seg & 63;
        keep_dilate_seg(bits3, carryA, LA, sizesA, ncompA, out,
                        img, s8 * 8, t, U.kd.kb, U.kd.db);
        __syncthreads();
    }
}

// ---------------------------------------------------------------------------
// Host side — memset(flags, 2 KB) + 1 regular dispatch
// ---------------------------------------------------------------------------
extern "C" void kernel_launch(void* const* d_in, const int* in_sizes, int n_in,
                              void* d_out, int out_size, void* d_ws, size_t ws_size,
                              hipStream_t stream) {
    const float* in = (const float*)d_in[0];
    float* out = (float*)d_out;

    uint8_t* ws = (uint8_t*)d_ws;
    int* LA      = (int*)ws;                                  // 16 MB
    int* sizesA  = (int*)(ws + (size_t)NTOT * 4);             // 16 MB
    int* LB      = (int*)(ws + (size_t)NTOT * 8);             // 16 MB
    int* sizesB  = (int*)(ws + (size_t)NTOT * 12);            // 16 MB
    uint64_t* bits1 = (uint64_t*)(ws + (size_t)NTOT * 16);    // 512 KB
    uint64_t* bits2 = bits1 + NWORDS;                         // 512 KB
    uint64_t* bits3 = bits2 + NWORDS;                         // 512 KB
    int* carryA = (int*)(bits3 + NWORDS);                     // 256 KB
    int* carryB = carryA + NWORDS;                            // 256 KB
    int* ncompA = carryB + NWORDS;                            // 64 B
    int* ncompB = ncompA + BATCH;                             // 64 B
    int* flags  = ncompB + BATCH;                             // 16 images x 32 ints

    hipMemsetAsync(flags, 0, BATCH * 32 * sizeof(int), stream);

    k_mega<<<NSTRIPS, 256, 0, stream>>>((const float4*)in, out,
                                        LA, sizesA, LB, sizesB,
                                        bits1, bits2, bits3,
                                        carryA, carryB, ncompA, ncompB, flags);
}

// Round 6
// 186.937 us; speedup vs baseline: 3.8570x; 1.0321x over previous
//
#include <hip/hip_runtime.h>
#include <stdint.h>

#define BATCH 16
#define H 512
#define W 512
#define HW (H * W)
#define NTOT (BATCH * HW)
#define NWORDS (NTOT / 64)      // 65536 packed words, 8 per row, 4096 per image

#define SROWS 16                // CCL strip = 16 rows
#define SWORDS 128              // words per CCL strip
#define SPIX 8192               // pixels per CCL strip
#define NSTRIPS (NWORDS / SWORDS)   // 512 strips (never straddle images)
#define IMG_STRIPS 32               // strips per image
#define NBOUND_IMG 248              // boundary words per image (31 rows x 8)

#define MAXR 4096                   // max runs per strip (128 words x 32)
#define NR (NSTRIPS * MAXR)         // run-id space: 2M ids, 8 MB per array

#define SPIN_LIMIT (1 << 20)        // hang-insurance: give up loudly, not hang

// ---------------------------------------------------------------------------
// Agent-scope relaxed accessors (sc1, coherence-point). Proven r3/r4: relaxed
// agent atomics are individually coherent across XCDs with NO fences; removing
// fences cut 269->135 us. r5 showed barriers are now cheap; the remaining cost
// was cold-HBM sparse touches of the 4x16MB pixel-indexed L/sizes arrays ->
// this version indexes union-find by RUN ID (touched set ~1MB, L2-resident).
// ---------------------------------------------------------------------------
__device__ __forceinline__ int ald(const int* p) {
    return __hip_atomic_load((int*)p, __ATOMIC_RELAXED, __HIP_MEMORY_SCOPE_AGENT);
}
__device__ __forceinline__ void ast(int* p, int v) {
    __hip_atomic_store(p, v, __ATOMIC_RELAXED, __HIP_MEMORY_SCOPE_AGENT);
}
__device__ __forceinline__ uint64_t ald64(const uint64_t* p) {
    return __hip_atomic_load((uint64_t*)p, __ATOMIC_RELAXED, __HIP_MEMORY_SCOPE_AGENT);
}
__device__ __forceinline__ void ast64(uint64_t* p, uint64_t v) {
    __hip_atomic_store(p, v, __ATOMIC_RELAXED, __HIP_MEMORY_SCOPE_AGENT);
}

// ---------------------------------------------------------------------------
// Union-find over run ids (global): atomicMin keeps parent <= child -> acyclic.
// ---------------------------------------------------------------------------
__device__ __forceinline__ int find_root_c(int* L, int x) {
    int r = x, p = ald(&L[r]);
    while (p != r) { r = p; p = ald(&L[r]); }
    if (ald(&L[x]) != r) atomicMin(&L[x], r);
    return r;
}

__device__ void merge_uf(int* L, int a, int b) {
    while (true) {
        a = find_root_c(L, a);
        b = find_root_c(L, b);
        if (a == b) return;
        int lo = a < b ? a : b;
        int hi = a < b ? b : a;
        int old = atomicMin(&L[hi], lo);
        if (old == hi) return;
        a = lo; b = old;
    }
}

__device__ __forceinline__ int find_root_lds(int* P, int x) {
    int r = x, p = P[r];
    while (p != r) { r = p; p = P[r]; }
    return r;
}

__device__ void merge_lds(int* P, int a, int b) {
    while (true) {
        a = find_root_lds(P, a);
        b = find_root_lds(P, b);
        if (a == b) return;
        int lo = a < b ? a : b;
        int hi = a < b ? b : a;
        int old = atomicMin(&P[hi], lo);
        if (old == hi) return;
        a = lo; b = old;
    }
}

// ---------------------------------------------------------------------------
// Run-id resolution. A word's runs: continuation run (if carry rid cv>=0, has
// no start bit) + new runs ranked 0..cnt-1 by position. wordrun[gw] = global
// rid of the word's FIRST NEW run. Run containing bit i:
//   - extends to bit0 & carry     -> cv
//   - extends to bit0 & no carry  -> wordrun (bit0 is rank-0 start)
//   - else start s = highest zero below i, +1; rid = wordrun + rank(s)
// ---------------------------------------------------------------------------
__device__ __forceinline__ int run_of(uint64_t m, int i, int cvrid, int wr) {
    uint64_t below = i ? ((~m) & ((1ull << i) - 1)) : 0ull;
    if (below == 0) return (cvrid >= 0) ? cvrid : wr;
    int s = 64 - __builtin_clzll(below);           // start bit of i's run
    uint64_t starts = m & ~((m << 1) | ((cvrid >= 0) ? 1ull : 0ull));
    return wr + __popcll(starts & ((1ull << s) - 1));
}

__device__ __forceinline__ int run_of_lds(uint64_t m, int i, int cvrid,
                                          uint64_t starts, int wb) {
    uint64_t below = i ? ((~m) & ((1ull << i) - 1)) : 0ull;
    if (below == 0) return (cvrid >= 0) ? cvrid : wb;
    int s = 64 - __builtin_clzll(below);
    return wb + __popcll(starts & ((1ull << s) - 1));
}

// remove-small transform of one word (fg comps; pure function of CCL data)
__device__ uint64_t keep_word(const uint64_t* __restrict__ bits,
                              const int* __restrict__ carry, const int* __restrict__ wordrun,
                              const int* __restrict__ L, const int* __restrict__ sizes,
                              const int* __restrict__ ncomp, int minsz, int gw) {
    uint64_t m = ald64(&bits[gw]);
    uint64_t res = m;
    if (m && ald(&ncomp[gw >> 12]) > 1) {
        int cv = ald(&carry[gw]);
        int wr = ald(&wordrun[gw]);
        int rk = 0;
        while (m) {
            int s = __builtin_ctzll(m);
            uint64_t rest = m >> s;
            uint64_t nr = ~rest;
            int len = nr ? __builtin_ctzll(nr) : (64 - s);
            uint64_t piece = ((len >= 64) ? ~0ull : ((1ull << len) - 1)) << s;
            bool initial = !(s == 0 && cv >= 0);
            int rid = initial ? (wr + rk++) : cv;
            if (ald(&sizes[ald(&L[rid])]) < minsz) res &= ~piece;
            m &= ~piece;
        }
    }
    return res;
}

// fill-holes transform of one word (bg comps; needs inv=1 CCL data)
__device__ uint64_t fill_word(const uint64_t* __restrict__ bits,
                              const int* __restrict__ carry, const int* __restrict__ wordrun,
                              const int* __restrict__ L, const int* __restrict__ sizes,
                              int minsz, int gw) {
    uint64_t fg = ald64(&bits[gw]);
    uint64_t bg = ~fg;
    uint64_t res = fg;
    int cv = ald(&carry[gw]);
    int wr = ald(&wordrun[gw]);
    int rk = 0;
    while (bg) {
        int s = __builtin_ctzll(bg);
        uint64_t rest = bg >> s;
        uint64_t nr = ~rest;
        int len = nr ? __builtin_ctzll(nr) : (64 - s);
        uint64_t piece = ((len >= 64) ? ~0ull : ((1ull << len) - 1)) << s;
        bool initial = !(s == 0 && cv >= 0);
        int rid = initial ? (wr + rk++) : cv;
        if (ald(&sizes[ald(&L[rid])]) < minsz) res |= piece;
        bg &= ~piece;
    }
    return res;
}

// one morph output word from an LDS window; gyTop = global row of local row 0
template <int R, bool ERODE>
__device__ uint64_t morph_word_lds(const uint64_t* buf, int lrow, int w, int gyTop) {
    const uint64_t BORDER = ERODE ? ~0ull : 0ull;
    uint64_t res = ERODE ? ~0ull : 0ull;
#pragma unroll
    for (int dy = -R; dy <= R; ++dy) {
        int lr = lrow + dy;
        int gy = gyTop + lr;
        if (gy < 0 || gy >= H) continue;       // image border rows = identity
        int v = R * R - dy * dy;
        int kx = 0;
        while ((kx + 1) * (kx + 1) <= v) ++kx;
        uint64_t cur = buf[lr * 8 + w];
        uint64_t prv = (w > 0) ? buf[lr * 8 + w - 1] : BORDER;
        uint64_t nxt = (w < 7) ? buf[lr * 8 + w + 1] : BORDER;
        uint64_t acc = cur;
#pragma unroll
        for (int dx = 1; dx <= kx; ++dx) {
            uint64_t right = (cur >> dx) | (nxt << (64 - dx));
            uint64_t left  = (cur << dx) | (prv >> (64 - dx));
            if (ERODE) acc &= right & left;
            else       acc |= right | left;
        }
        if (ERODE) res &= acc;
        else       res |= acc;
    }
    return res;
}

// ---------------------------------------------------------------------------
// Strip-local CCL body, RUN-ID edition (blockDim 256; t >= SWORDS pass m = 0).
// 1. per-word new-run count cnt (cont flag is local: left word's bit63)
// 2. inclusive prefix scan -> wbL (exclusive base = wbL - cnt)
// 3. per-row rid-carry walk (scarry[lw] = rid continuing INTO word lw)
// 4. par[] identity over run ids; vertical unions via run_of_lds
// 5. publish depth-1 trees into L (rid space), sizes=0 at roots,
//    carry[] = global rid of continuation, wordrun[] = global first-run rid
// ---------------------------------------------------------------------------
__device__ void strip_ccl_body(uint64_t m, uint64_t* sw, int* scarry,
                               int* cntL, int* wbL, int* par,
                               int blk, int t,
                               int* __restrict__ carry, int* __restrict__ wordrun,
                               int* __restrict__ L, int* __restrict__ sizes,
                               int* __restrict__ ncomp) {
    if (t < SWORDS) sw[t] = m;
    __syncthreads();

    if (t < SWORDS) {                   // per-word new-run count
        bool cont = (t & 7) ? ((sw[t - 1] >> 63) != 0) : false;
        int c = __popcll(m & ~(m << 1));
        if ((m & 1ull) && cont) --c;
        cntL[t] = c;
        wbL[t] = c;
    }
    __syncthreads();
    for (int off = 1; off < SWORDS; off <<= 1) {   // inclusive scan (128)
        int v = 0;
        if (t < SWORDS && t >= off) v = wbL[t - off];
        __syncthreads();
        if (t < SWORDS) wbL[t] += v;
        __syncthreads();
    }

    if (t < SROWS) {                    // per-row rid carries
        int cv = -1;
        for (int i = 0; i < 8; ++i) {
            int lw = t * 8 + i;
            scarry[lw] = cv;
            uint64_t w = sw[lw];
            if (w >> 63) { if (cntL[lw] > 0) cv = wbL[lw] - 1; }  // last start's rid
            else cv = -1;
        }
    }
    for (int i = t; i < MAXR; i += 256) par[i] = i;   // identity init
    __syncthreads();

    int cv = -1, wb = 0;
    uint64_t starts = 0ull;
    if (t < SWORDS) {
        cv = scarry[t];
        wb = wbL[t] - cntL[t];          // exclusive base
        ast(&carry[blk * SWORDS + t], (cv >= 0) ? (blk * MAXR + cv) : -1);
        ast(&wordrun[blk * SWORDS + t], blk * MAXR + wb);
        starts = m & ~((m << 1) | ((cv >= 0) ? 1ull : 0ull));
    }
    __syncthreads();

    if (t >= 8 && t < SWORDS && m) {    // intra-strip vertical unions
        uint64_t up = sw[t - 8];
        uint64_t cand = m & up;
        if (cand) {
            uint64_t curprev = (t & 7) ? sw[t - 1] : 0ull;
            uint64_t upprev  = (t & 7) ? sw[t - 9] : 0ull;
            uint64_t curl = (m << 1) | (curprev >> 63);
            uint64_t upl  = (up << 1) | (upprev >> 63);
            cand &= ~(curl & upl);
            int cvu = scarry[t - 8];
            int wbu = wbL[t - 8] - cntL[t - 8];
            uint64_t startsU = up & ~((up << 1) | ((cvu >= 0) ? 1ull : 0ull));
            while (cand) {
                int i = __builtin_ctzll(cand);
                int sP = run_of_lds(m, i, cv, starts, wb);
                int sQ = run_of_lds(up, i, cvu, startsU, wbu);
                merge_lds(par, sP, sQ);
                cand &= cand - 1;
            }
        }
    }
    __syncthreads();

    if (t < SWORDS) {                   // publish depth-1 trees (rid space)
        int g = blk * MAXR;
        uint64_t ss = starts;
        int rk = 0;
        while (ss) {
            int rid = wb + rk; ++rk;
            int r = find_root_lds(par, rid);
            ast(&L[g + rid], g + r);
            if (r == rid) ast(&sizes[g + rid], 0);
            ss &= ss - 1;
        }
    }
    if (t == 0 && (blk & 31) == 0) ast(&ncomp[blk >> 5], 0);  // 32 strips/image
}

// one cross-strip boundary word (y % 16 == 0, y != 0)
__device__ void merge_bound_item(const uint64_t* __restrict__ bits, uint64_t inv64,
                                 const int* __restrict__ carry,
                                 const int* __restrict__ wordrun,
                                 int* __restrict__ L, int gw, int w) {
    uint64_t cur = ald64(&bits[gw]) ^ inv64;
    uint64_t up  = ald64(&bits[gw - 8]) ^ inv64;
    uint64_t cand = cur & up;
    if (!cand) return;
    uint64_t curprev = w ? (ald64(&bits[gw - 1]) ^ inv64) : 0ull;
    uint64_t upprev  = w ? (ald64(&bits[gw - 9]) ^ inv64) : 0ull;
    uint64_t curl = (cur << 1) | (curprev >> 63);
    uint64_t upl  = (up << 1)  | (upprev >> 63);
    cand &= ~(curl & upl);
    if (!cand) return;
    int cvc = ald(&carry[gw]), cvu = ald(&carry[gw - 8]);
    int wrc = ald(&wordrun[gw]), wru = ald(&wordrun[gw - 8]);
    while (cand) {
        int i = __builtin_ctzll(cand);
        int sP = run_of(cur, i, cvc, wrc);
        int sQ = run_of(up, i, cvu, wru);
        merge_uf(L, sP, sQ);
        cand &= cand - 1;
    }
}

// flatten+count for one strip's 128 words (per-block LDS hash, rid space)
__device__ void flatten_block(const uint64_t* __restrict__ bits, uint64_t inv64,
                              const int* __restrict__ carry,
                              const int* __restrict__ wordrun,
                              int* __restrict__ L,
                              int* __restrict__ sizes, int* __restrict__ ncomp,
                              int blk, int t, int* hk, int* hv) {
    if (t < 128) { hk[t] = -1; hv[t] = 0; }
    __syncthreads();
    if (t < SWORDS) {
        int gw = blk * SWORDS + t;
        uint64_t m = ald64(&bits[gw]) ^ inv64;
        if (m) {
            int cv = ald(&carry[gw]);
            int wr = ald(&wordrun[gw]);
            int rk = 0;
            while (m) {
                int s = __builtin_ctzll(m);
                uint64_t rest = m >> s;
                uint64_t nr = ~rest;
                int len = nr ? __builtin_ctzll(nr) : (64 - s);
                uint64_t piece = ((len >= 64) ? ~0ull : ((1ull << len) - 1)) << s;
                bool initial = !(s == 0 && cv >= 0);
                int rid = initial ? (wr + rk++) : cv;
                int r = find_root_c(L, rid);
                if (initial && r == rid) atomicAdd(&ncomp[gw >> 12], 1);
                int cnt = __popcll(piece);
                uint32_t h = ((uint32_t)r * 2654435761u) >> 25;
                bool done = false;
                for (int tt = 0; tt < 16; ++tt) {
                    int slot = (h + tt) & 127;
                    int k = hk[slot];
                    if (k == -1) k = atomicCAS(&hk[slot], -1, r);
                    if (k == -1 || k == r) { atomicAdd(&hv[slot], cnt); done = true; break; }
                }
                if (!done) atomicAdd(&sizes[r], cnt);
                m &= ~piece;
            }
        }
    }
    __syncthreads();
    if (t < 128 && hk[t] != -1) atomicAdd(&sizes[hk[t]], hv[t]);
}

// keep + dilate(disk1) + float4 cast for one 8-row segment (256 threads)
__device__ void keep_dilate_seg(const uint64_t* __restrict__ bits,
                                const int* __restrict__ carry,
                                const int* __restrict__ wordrun,
                                const int* __restrict__ L,
                                const int* __restrict__ sizes,
                                const int* __restrict__ ncomp,
                                float* __restrict__ out,
                                int img, int y0, int t, uint64_t* kb, uint64_t* db) {
    if (t < 80) {
        int lr = t >> 3;
        int w = t & 7;
        int gy = y0 - 1 + lr;
        uint64_t v = 0;
        if (gy >= 0 && gy < H)
            v = keep_word(bits, carry, wordrun, L, sizes, ncomp, 2000,
                          img * 4096 + gy * 8 + w);
        kb[t] = v;
    }
    __syncthreads();
    if (t < 64) {
        int r = t >> 3, w = t & 7;
        uint64_t cur = kb[(r + 1) * 8 + w];
        uint64_t up  = kb[r * 8 + w];
        uint64_t dn  = kb[(r + 2) * 8 + w];
        uint64_t prv = w ? kb[(r + 1) * 8 + w - 1] : 0ull;
        uint64_t nxt = (w < 7) ? kb[(r + 1) * 8 + w + 1] : 0ull;
        db[t] = cur | up | dn | (cur << 1) | (prv >> 63) | (cur >> 1) | (nxt << 63);
    }
    __syncthreads();

    int q0 = t * 16;                    // 16 consecutive pixels per thread
    uint64_t wd = db[q0 >> 6];
    int sh = q0 & 63;
    float4* o = (float4*)(out + (size_t)img * HW + (size_t)y0 * W + q0);
#pragma unroll
    for (int k = 0; k < 4; ++k) {
        uint32_t nib = (uint32_t)(wd >> (sh + k * 4)) & 0xFu;
        float4 f;
        f.x = (nib & 1u) ? 1.0f : 0.0f;
        f.y = (nib & 2u) ? 1.0f : 0.0f;
        f.z = (nib & 4u) ? 1.0f : 0.0f;
        f.w = (nib & 8u) ? 1.0f : 0.0f;
        o[k] = f;
    }
}

// ---------------------------------------------------------------------------
// PER-IMAGE fence-free barrier (proven r5): sync only the 32 blocks of one
// image. Release = vmcnt(0) (sc1 stores ack'd at coherence point), arrival =
// own flag store, detection = 32 threads poll the image's 32 flags.
// ---------------------------------------------------------------------------
__device__ __forceinline__ void ibar(int* flags, int img, int si, int phase) {
    int* base = flags + img * 32;
    __syncthreads();
    if (threadIdx.x == 0) {
        asm volatile("s_waitcnt vmcnt(0)" ::: "memory");   // release: stores ack'd
        ast(&base[si], phase);
    }
    if (threadIdx.x < 32) {
        int spins = 0;
        while (ald(&base[threadIdx.x]) < phase && ++spins < SPIN_LIMIT)
            __builtin_amdgcn_s_sleep(1);
    }
    __syncthreads();
}

// ---------------------------------------------------------------------------
// MEGA: whole pipeline, ONE regular kernel, 9 per-image barriers, run-id UF.
// 512 blocks x 256 thr, ~18.6 KB LDS, __launch_bounds__(256,2).
// ---------------------------------------------------------------------------
__global__ __launch_bounds__(256, 2) void k_mega(
        const float4* __restrict__ in4, float* __restrict__ out,
        int* LA, int* sizesA, int* LB, int* sizesB,
        uint64_t* bits1, uint64_t* bits2, uint64_t* bits3,
        int* carryA, int* carryB, int* wordrunA, int* wordrunB,
        int* ncompA, int* ncompB, int* flags) {
    __shared__ uint64_t sw[SWORDS];
    __shared__ int scarry[SWORDS];
    __shared__ int cntL[SWORDS];
    __shared__ int wbL[SWORDS];
    __shared__ union US {
        int par[MAXR];                                     // 16 KB (CCL)
        struct { uint64_t A[320]; uint64_t B[320]; } mo;   // 5 KB (morph)
        struct { int hk[128]; int hv[128]; } ha;           // 1 KB (flatten hash)
        struct { uint64_t kb[80]; uint64_t db[64]; } kd;   // 1.1 KB (out stage)
    } U;
    int blk = blockIdx.x;
    int t = threadIdx.x;
    int img = blk >> 5, si = blk & 31;   // image id, strip-in-image

    // P0: threshold + pack, STRIP-LOCAL (block packs its own 128 words)
#pragma unroll
    for (int it = 0; it < 8; ++it) {
        int q = blk * (SPIX / 4) + it * 256 + t;           // quad index
        float4 v = in4[q];
        uint32_t nib = (v.x > 0.0f ? 1u : 0u) | (v.y > 0.0f ? 2u : 0u) |
                       (v.z > 0.0f ? 4u : 0u) | (v.w > 0.0f ? 8u : 0u);
        uint64_t val = (uint64_t)nib << (4 * (t & 15));
        val |= __shfl_xor(val, 1);
        val |= __shfl_xor(val, 2);
        val |= __shfl_xor(val, 4);
        val |= __shfl_xor(val, 8);
        if ((t & 15) == 0) ast64(&bits1[q >> 4], val);
    }
    __syncthreads();

    // P1: CCL1 strip phase (fg of bits1) -> set A
    {
        uint64_t m = (t < SWORDS) ? ald64(&bits1[blk * SWORDS + t]) : 0ull;
        strip_ccl_body(m, sw, scarry, cntL, wbL, U.par, blk, t,
                       carryA, wordrunA, LA, sizesA, ncompA);
    }
    ibar(flags, img, si, 1);

    // P2: cross-strip merges (bits1, fg) — image-local: 248 items / 32 blocks
    if (t < 8) {
        int item = si * 8 + t;
        if (item < NBOUND_IMG) {
            int gw = img * 4096 + ((item >> 3) + 1) * SROWS * 8 + (item & 7);
            merge_bound_item(bits1, 0ull, carryA, wordrunA, LA, gw, item & 7);
        }
    }
    ibar(flags, img, si, 2);

    // P3: flatten + count (bits1, fg) -> sizesA, ncompA
    flatten_block(bits1, 0ull, carryA, wordrunA, LA, sizesA, ncompA,
                  blk, t, U.ha.hk, U.ha.hv);
    ibar(flags, img, si, 3);

    // P4: remove_small_objects(2000,guard) -> bits2, fused with CCL2 strip (bg)
    {
        uint64_t m = 0ull;
        if (t < SWORDS) {
            int gw = blk * SWORDS + t;
            uint64_t kw = keep_word(bits1, carryA, wordrunA, LA, sizesA, ncompA,
                                    2000, gw);
            ast64(&bits2[gw], kw);
            m = ~kw;
        }
        strip_ccl_body(m, sw, scarry, cntL, wbL, U.par, blk, t,
                       carryB, wordrunB, LB, sizesB, ncompB);
    }
    ibar(flags, img, si, 4);

    // P5: cross-strip merges (bits2, bg)
    if (t < 8) {
        int item = si * 8 + t;
        if (item < NBOUND_IMG) {
            int gw = img * 4096 + ((item >> 3) + 1) * SROWS * 8 + (item & 7);
            merge_bound_item(bits2, ~0ull, carryB, wordrunB, LB, gw, item & 7);
        }
    }
    ibar(flags, img, si, 5);

    // P6: flatten + count (bits2, bg) -> sizesB
    flatten_block(bits2, ~0ull, carryB, wordrunB, LB, sizesB, ncompB,
                  blk, t, U.ha.hk, U.ha.hv);
    ibar(flags, img, si, 6);

    // P7: fill_holes(<301) + erode(d2) + opening(d5) + CCL3 strip -> bits3, set A
    {
        int gyTop = si * 16 - 12;
        for (int lw = t; lw < 320; lw += 256) {              // load + fill-holes
            int gy = gyTop + (lw >> 3);
            int w = lw & 7;
            uint64_t v = 0;
            if (gy >= 0 && gy < H)
                v = fill_word(bits2, carryB, wordrunB, LB, sizesB, 301,
                              img * 4096 + gy * 8 + w);
            U.mo.A[lw] = v;
        }
        __syncthreads();
        for (int lw = t; lw < 320; lw += 256) {              // erode disk(2)
            int lr = lw >> 3;
            if (lr >= 2 && lr <= 37) U.mo.B[lw] = morph_word_lds<2, true>(U.mo.A, lr, lw & 7, gyTop);
        }
        __syncthreads();
        for (int lw = t; lw < 320; lw += 256) {              // erode disk(5)
            int lr = lw >> 3;
            if (lr >= 7 && lr <= 32) U.mo.A[lw] = morph_word_lds<5, true>(U.mo.B, lr, lw & 7, gyTop);
        }
        __syncthreads();
        for (int lw = t; lw < 320; lw += 256) {              // dilate disk(5)
            int lr = lw >> 3;
            if (lr >= 12 && lr <= 27) U.mo.B[lw] = morph_word_lds<5, false>(U.mo.A, lr, lw & 7, gyTop);
        }
        __syncthreads();
        uint64_t m3 = 0ull;
        if (t < SWORDS) {
            m3 = U.mo.B[t + 96];        // local rows 12..27 = this strip
            ast64(&bits3[blk * SWORDS + t], m3);
        }
        // par aliases mo — safe: all mo.B reads (m3) happen before body's first
        // par write, which is behind multiple __syncthreads
        strip_ccl_body(m3, sw, scarry, cntL, wbL, U.par, blk, t,
                       carryA, wordrunA, LA, sizesA, ncompA);
    }
    ibar(flags, img, si, 7);

    // P8: cross-strip merges (bits3, fg)
    if (t < 8) {
        int item = si * 8 + t;
        if (item < NBOUND_IMG) {
            int gw = img * 4096 + ((item >> 3) + 1) * SROWS * 8 + (item & 7);
            merge_bound_item(bits3, 0ull, carryA, wordrunA, LA, gw, item & 7);
        }
    }
    ibar(flags, img, si, 8);

    // P9: flatten + count (bits3, fg) -> sizesA, ncompA
    flatten_block(bits3, 0ull, carryA, wordrunA, LA, sizesA, ncompA,
                  blk, t, U.ha.hk, U.ha.hv);
    ibar(flags, img, si, 9);

    // P10: remove_small_objects(2000,guard) + dilate(d1) + float4 out
    // 64 8-row segments per image -> 2 per block (image-local)
    for (int k = 0; k < 2; ++k) {
        int seg = blk * 2 + k;          // seg>>6 == img by construction
        int s8 = seg & 63;
        keep_dilate_seg(bits3, carryA, wordrunA, LA, sizesA, ncompA, out,
                        img, s8 * 8, t, U.kd.kb, U.kd.db);
        __syncthreads();
    }
}

// ---------------------------------------------------------------------------
// Host side — memset(flags, 2 KB) + 1 regular dispatch
// ---------------------------------------------------------------------------
extern "C" void kernel_launch(void* const* d_in, const int* in_sizes, int n_in,
                              void* d_out, int out_size, void* d_ws, size_t ws_size,
                              hipStream_t stream) {
    const float* in = (const float*)d_in[0];
    float* out = (float*)d_out;

    uint8_t* ws = (uint8_t*)d_ws;
    int* LA      = (int*)ws;                                  // 8 MB (rid space)
    int* sizesA  = LA + NR;                                   // 8 MB
    int* LB      = sizesA + NR;                               // 8 MB
    int* sizesB  = LB + NR;                                   // 8 MB
    uint64_t* bits1 = (uint64_t*)(sizesB + NR);               // 512 KB
    uint64_t* bits2 = bits1 + NWORDS;                         // 512 KB
    uint64_t* bits3 = bits2 + NWORDS;                         // 512 KB
    int* carryA   = (int*)(bits3 + NWORDS);                   // 256 KB
    int* carryB   = carryA + NWORDS;                          // 256 KB
    int* wordrunA = carryB + NWORDS;                          // 256 KB
    int* wordrunB = wordrunA + NWORDS;                        // 256 KB
    int* ncompA   = wordrunB + NWORDS;                        // 64 B
    int* ncompB   = ncompA + BATCH;                           // 64 B
    int* flags    = ncompB + BATCH;                           // 16 images x 32 ints

    hipMemsetAsync(flags, 0, BATCH * 32 * sizeof(int), stream);

    k_mega<<<NSTRIPS, 256, 0, stream>>>((const float4*)in, out,
                                        LA, sizesA, LB, sizesB,
                                        bits1, bits2, bits3,
                                        carryA, carryB, wordrunA, wordrunB,
                                        ncompA, ncompB, flags);
}